// Round 8
// baseline (286.869 us; speedup 1.0000x reference)
//
#include <hip/hip_runtime.h>
#include <hip/hip_bf16.h>

#define NN 20000
#define NE 200000

typedef __bf16 bf16x8 __attribute__((ext_vector_type(8)));
typedef float f32x4 __attribute__((ext_vector_type(4)));
typedef unsigned short u16x8 __attribute__((ext_vector_type(8)));

// ---- workspace layout (bytes) ----
constexpr int TAB_MSG_SCALE = 0;      // f32 element offsets within tabs
constexpr int TAB_MSG_BETA  = 256;
constexpr int TAB_UPD_SCALE = 512;
constexpr int TAB_UPD_BETA  = 768;
constexpr int TAB_TASKC     = 1024;   // task @ att_W1[768:1024] + att_b1
constexpr int TAB_EM        = 1280;   // 16*256  e@msg_W + msg_b
constexpr int TAB_EC        = 1280 + 4096; // 16*256  e@att_W1[512:768]
constexpr size_t OFF_WPRET = 40960;    // u16[768*256] n-major
constexpr size_t OFF_W1T   = 434176;   // u16[256*512]
constexpr size_t OFF_W2T   = 696320;   // u16[256*256]
constexpr size_t OFF_CNT   = 827392;   // i32[NN]
constexpr size_t OFF_PTRS  = 907392;   // i32[NN+1]
constexpr size_t OFF_PWORK = 987648;   // i32[NN]
constexpr size_t OFF_SRCET = 1067648;  // u32[NE]  src | et<<16 (CSR order)
constexpr size_t OFF_UPDB  = 1867648;  // u16[NN*256]  aggregated+modulated upd half (bf16)
constexpr size_t OFF_G     = 12107648; // u16[NN*512]  interleaved [P1|M] per 4-dim group
constexpr size_t OFF_P2B   = 32587648; // u16[NN*256]  P2 + taskc (bf16)
constexpr size_t WS_NEED   = 42827648;

__device__ __forceinline__ float bf2f(unsigned short u){
  union { unsigned int i; float f; } v; v.i = ((unsigned int)u) << 16; return v.f;
}
__device__ __forceinline__ unsigned short f2bf(float f){
  __bf16 h = (__bf16)f; unsigned short u; __builtin_memcpy(&u, &h, 2); return u;
}
__device__ __forceinline__ float gelu_f(float x){
  return 0.5f * x * (1.0f + erff(x * 0.70710678118654752f));
}
// fast sigmoid-gelu: max abs err ~0.01 vs exact
__device__ __forceinline__ float gelu_fast(float x){
  return x / (1.0f + __expf(-1.702f * x));
}
// overflow-safe fast tanh
__device__ __forceinline__ float tanh_fast(float x){
  float e = __expf(2.0f * x);
  return 1.0f - 2.0f / (e + 1.0f);
}

// ---------------- K0: tiny tables (proven) ----------------
__global__ __launch_bounds__(256) void k_tables(
    const float* __restrict__ task, const float* __restrict__ eemb,
    const float* __restrict__ msg_W, const float* __restrict__ msg_b,
    const float* __restrict__ att_W1, const float* __restrict__ att_b1,
    const float* __restrict__ ma_W1, const float* __restrict__ ma_b1,
    const float* __restrict__ ma_W2, const float* __restrict__ ma_b2,
    const float* __restrict__ ua_W1, const float* __restrict__ ua_b1,
    const float* __restrict__ ua_W2, const float* __restrict__ ua_b2,
    float* __restrict__ tabs)
{
  __shared__ float s_in[512];
  __shared__ float s_h[512];
  int b = blockIdx.x, tid = threadIdx.x;
  if (b < 2){
    const float* W1 = b ? ua_W1 : ma_W1;  const float* b1 = b ? ua_b1 : ma_b1;
    const float* W2 = b ? ua_W2 : ma_W2;  const float* b2 = b ? ua_b2 : ma_b2;
    s_in[tid] = task[tid];
    __syncthreads();
    #pragma unroll
    for (int jj = 0; jj < 2; ++jj){
      int j = tid + jj*256;
      float acc = b1[j];
      for (int k = 0; k < 256; ++k) acc += s_in[k] * W1[k*512 + j];
      s_h[j] = gelu_f(acc);
    }
    __syncthreads();
    float o[2];
    #pragma unroll
    for (int jj = 0; jj < 2; ++jj){
      int j = tid + jj*256;
      float acc = b2[j];
      for (int k = 0; k < 512; ++k) acc += s_h[k] * W2[k*512 + j];
      o[jj] = acc;
    }
    float* scale = tabs + (b ? TAB_UPD_SCALE : TAB_MSG_SCALE);
    float* beta  = tabs + (b ? TAB_UPD_BETA  : TAB_MSG_BETA);
    scale[tid] = 1.0f + 0.5f * tanhf(o[0]);
    beta[tid]  = o[1];
  } else if (b == 2){
    s_in[tid] = task[tid];
    __syncthreads();
    float acc = att_b1[tid];
    for (int k = 0; k < 256; ++k) acc += s_in[k] * att_W1[(768 + k)*256 + tid];
    tabs[TAB_TASKC + tid] = acc;
  } else if (b < 19){
    int t = b - 3;
    s_in[tid] = eemb[t*256 + tid];
    __syncthreads();
    float acc = msg_b[tid];
    for (int k = 0; k < 256; ++k) acc += s_in[k] * msg_W[k*256 + tid];
    tabs[TAB_EM + t*256 + tid] = acc;
  } else {
    int t = b - 19;
    s_in[tid] = eemb[t*256 + tid];
    __syncthreads();
    float acc = 0.f;
    for (int k = 0; k < 256; ++k) acc += s_in[k] * att_W1[(512 + k)*256 + tid];
    tabs[TAB_EC + t*256 + tid] = acc;
  }
}

// ---------------- K0b: bf16 transposed weight copies (proven) ----------------
__global__ __launch_bounds__(256) void k_prep(
    const float* __restrict__ msg_W, const float* __restrict__ att_W1,
    const float* __restrict__ up_W1, const float* __restrict__ up_W2,
    unsigned short* __restrict__ WpreT, unsigned short* __restrict__ W1T,
    unsigned short* __restrict__ W2T)
{
  int b = blockIdx.x, tid = threadIdx.x;
  if (b < 768){
    int n = b;
    float v;
    if (n < 256)      v = msg_W[tid*256 + n];
    else if (n < 512) v = att_W1[tid*256 + (n - 256)];
    else              v = att_W1[(256 + tid)*256 + (n - 512)];
    WpreT[n*256 + tid] = f2bf(v);
  } else if (b < 1024){
    int n = b - 768;
    W1T[n*512 + tid]       = f2bf(up_W1[tid*256 + n]);
    W1T[n*512 + 256 + tid] = f2bf(up_W1[(256 + tid)*256 + n]);
  } else {
    int n = b - 1024;
    W2T[n*256 + tid] = f2bf(up_W2[tid*256 + n]);
  }
}

// ---------------- K1: G=[P1|M interleaved], P2b (proven) ----------------
__global__ __launch_bounds__(256) void k_gemm_pre(
    const float* __restrict__ X, const unsigned short* __restrict__ WpreT,
    const float* __restrict__ tabs,
    unsigned short* __restrict__ G, unsigned short* __restrict__ P2b)
{
  __shared__ __align__(16) unsigned short s_b[16*256]; // 8KB, swizzled elem ^= (n&7)<<3
  int tid = threadIdx.x, wv = tid >> 6, lane = tid & 63;
  int m0 = blockIdx.x*64 + wv*16;
  bool valid = (m0 < NN);
  int lo = lane & 15, hi = lane >> 4;
  bf16x8 a[8];
  if (valid){
    const float* xrow = X + (size_t)(m0 + lo)*256 + hi*8;
    #pragma unroll
    for (int kc = 0; kc < 8; ++kc){
      float4 f0 = *(const float4*)(xrow + kc*32);
      float4 f1 = *(const float4*)(xrow + kc*32 + 4);
      bf16x8 v;
      v[0]=(__bf16)f0.x; v[1]=(__bf16)f0.y; v[2]=(__bf16)f0.z; v[3]=(__bf16)f0.w;
      v[4]=(__bf16)f1.x; v[5]=(__bf16)f1.y; v[6]=(__bf16)f1.z; v[7]=(__bf16)f1.w;
      a[kc] = v;
    }
  }
  int sn = tid >> 4, sk0 = (tid & 15)*16;
  int sswz = (sn & 7) << 3;
  int rswz = (lo & 7) << 3;
  for (int nt = 0; nt < 48; ++nt){
    __syncthreads();
    {
      const unsigned short* gsrc = WpreT + (size_t)(nt*16 + sn)*256 + sk0;
      uint4 d0 = *(const uint4*)(gsrc);
      uint4 d1 = *(const uint4*)(gsrc + 8);
      *(uint4*)(s_b + sn*256 + (sk0 ^ sswz))       = d0;
      *(uint4*)(s_b + sn*256 + ((sk0 + 8) ^ sswz)) = d1;
    }
    __syncthreads();
    if (!valid) continue;
    f32x4 acc = {0.f, 0.f, 0.f, 0.f};
    #pragma unroll
    for (int kc = 0; kc < 8; ++kc){
      bf16x8 bfrag = *(const bf16x8*)(s_b + lo*256 + ((kc*32 + hi*8) ^ rswz));
      acc = __builtin_amdgcn_mfma_f32_16x16x32_bf16(a[kc], bfrag, acc, 0, 0, 0);
    }
    int n0 = nt*16;
    if (nt < 16){
      int j = n0 + lo;
      int elem = ((j >> 2) << 3) + 4 + (j & 3);
      unsigned short* grow = G + (size_t)(m0 + hi*4)*512 + elem;
      #pragma unroll
      for (int r = 0; r < 4; ++r) grow[(size_t)r*512] = f2bf(acc[r]);
    } else if (nt < 32){
      int j = n0 - 256 + lo;
      int elem = ((j >> 2) << 3) + (j & 3);
      unsigned short* grow = G + (size_t)(m0 + hi*4)*512 + elem;
      #pragma unroll
      for (int r = 0; r < 4; ++r) grow[(size_t)r*512] = f2bf(acc[r]);
    } else {
      int j = n0 - 512 + lo;
      float tcadd = tabs[TAB_TASKC + j];
      unsigned short* prow = P2b + (size_t)(m0 + hi*4)*256 + j;
      #pragma unroll
      for (int r = 0; r < 4; ++r) prow[(size_t)r*256] = f2bf(acc[r] + tcadd);
    }
  }
}

// ---------------- K2a: in-degree histogram ----------------
__global__ __launch_bounds__(256) void k_hist(
    const int* __restrict__ eidx, int* __restrict__ cnt)
{
  int e = blockIdx.x*256 + threadIdx.x;
  if (e < NE) atomicAdd(&cnt[eidx[NE + e]], 1);
}

// ---------------- K2b: exclusive prefix sum (1 block, 20 elems/thread) ----------------
__global__ __launch_bounds__(1024) void k_scan(
    const int* __restrict__ cnt, int* __restrict__ ptrs, int* __restrict__ pwork)
{
  __shared__ int s[1024];
  int tid = threadIdx.x;
  int loc[20];
  int tot = 0;
  #pragma unroll
  for (int j = 0; j < 20; ++j){
    int i = tid*20 + j;
    loc[j] = tot;
    tot += (i < NN) ? cnt[i] : 0;
  }
  s[tid] = tot;
  __syncthreads();
  #pragma unroll
  for (int off = 1; off < 1024; off <<= 1){
    int t = (tid >= off) ? s[tid - off] : 0;
    __syncthreads();
    s[tid] += t;
    __syncthreads();
  }
  int base = s[tid] - tot;
  #pragma unroll
  for (int j = 0; j < 20; ++j){
    int i = tid*20 + j;
    if (i < NN){
      ptrs[i]  = base + loc[j];
      pwork[i] = base + loc[j];
    }
  }
  if (tid == 1023) ptrs[NN] = s[1023];
}

// ---------------- K2c: CSR build ----------------
__global__ __launch_bounds__(256) void k_csr_build(
    const int* __restrict__ eidx, const int* __restrict__ etype,
    int* __restrict__ pwork, unsigned int* __restrict__ srcet)
{
  int e = blockIdx.x*256 + threadIdx.x;
  if (e < NE){
    int dst = eidx[NE + e];
    int pos = atomicAdd(&pwork[dst], 1);
    srcet[pos] = (unsigned int)eidx[e] | ((unsigned int)etype[e] << 16);
  }
}

// ---------------- K3 v2: attention + aggregate, 4 edges/wave-iter, 16 lanes/edge ----------------
// lane = 16*grp + l: processes edge (i+grp), dims [16l, 16l+16).
// G row: dim j -> elems {(j>>2)*8 + (j&3)} = P1, +4 = M; lane's 16 dims = 64B contiguous.
__global__ __launch_bounds__(256) void k_agg(
    const int* __restrict__ ptrs, const unsigned int* __restrict__ srcet,
    const unsigned short* __restrict__ G, const unsigned short* __restrict__ P2b,
    const float* __restrict__ tabs, const float* __restrict__ attW2,
    const float* __restrict__ attb2, const float* __restrict__ escale,
    unsigned short* __restrict__ updB)
{
  int node = blockIdx.x*4 + (threadIdx.x >> 6);
  if (node >= NN) return;
  int lane = threadIdx.x & 63;
  int grp = lane >> 4, l = lane & 15;
  int d0 = l*16;
  float sc = escale[0], bb = attb2[0];

  // loop-invariant per-lane state: q (P2b+taskc) and att_W2 slice, 16 dims each
  float q[16], wv2[16];
  {
    const unsigned short* p2 = P2b + (size_t)node*256 + d0;
    u16x8 pa = *(const u16x8*)(p2);
    u16x8 pb = *(const u16x8*)(p2 + 8);
    #pragma unroll
    for (int j = 0; j < 8; ++j){ q[j] = bf2f(pa[j]); q[8 + j] = bf2f(pb[j]); }
    #pragma unroll
    for (int c = 0; c < 4; ++c){
      float4 t = *(const float4*)(attW2 + d0 + c*4);
      wv2[c*4+0] = t.x; wv2[c*4+1] = t.y; wv2[c*4+2] = t.z; wv2[c*4+3] = t.w;
    }
  }

  int start = ptrs[node], end = ptrs[node + 1];
  float acc[16];
  #pragma unroll
  for (int j = 0; j < 16; ++j) acc[j] = 0.f;
  float W = 0.f;

  for (int i = start; i < end; i += 4){
    int idx = i + grp;
    bool valid = (idx < end);
    int cidx = valid ? idx : (end - 1);
    unsigned int se = srcet[cidx];
    int src = (int)(se & 0xFFFFu), et = (int)(se >> 16);
    const unsigned short* grow = G + (size_t)src*512 + d0*2;
    u16x8 g0 = *(const u16x8*)(grow);
    u16x8 g1 = *(const u16x8*)(grow + 8);
    u16x8 g2 = *(const u16x8*)(grow + 16);
    u16x8 g3 = *(const u16x8*)(grow + 24);
    const float* ecp = tabs + TAB_EC + et*256 + d0;
    const float* emp = tabs + TAB_EM + et*256 + d0;
    float4 ec0 = *(const float4*)(ecp);
    float4 ec1 = *(const float4*)(ecp + 4);
    float4 ec2 = *(const float4*)(ecp + 8);
    float4 ec3 = *(const float4*)(ecp + 12);
    float part =
        gelu_fast(bf2f(g0[0]) + q[0]  + ec0.x)*wv2[0]
      + gelu_fast(bf2f(g0[1]) + q[1]  + ec0.y)*wv2[1]
      + gelu_fast(bf2f(g0[2]) + q[2]  + ec0.z)*wv2[2]
      + gelu_fast(bf2f(g0[3]) + q[3]  + ec0.w)*wv2[3]
      + gelu_fast(bf2f(g1[0]) + q[4]  + ec1.x)*wv2[4]
      + gelu_fast(bf2f(g1[1]) + q[5]  + ec1.y)*wv2[5]
      + gelu_fast(bf2f(g1[2]) + q[6]  + ec1.z)*wv2[6]
      + gelu_fast(bf2f(g1[3]) + q[7]  + ec1.w)*wv2[7]
      + gelu_fast(bf2f(g2[0]) + q[8]  + ec2.x)*wv2[8]
      + gelu_fast(bf2f(g2[1]) + q[9]  + ec2.y)*wv2[9]
      + gelu_fast(bf2f(g2[2]) + q[10] + ec2.z)*wv2[10]
      + gelu_fast(bf2f(g2[3]) + q[11] + ec2.w)*wv2[11]
      + gelu_fast(bf2f(g3[0]) + q[12] + ec3.x)*wv2[12]
      + gelu_fast(bf2f(g3[1]) + q[13] + ec3.y)*wv2[13]
      + gelu_fast(bf2f(g3[2]) + q[14] + ec3.z)*wv2[14]
      + gelu_fast(bf2f(g3[3]) + q[15] + ec3.w)*wv2[15];
    // reduce within the 16-lane group (XOR offsets < 16 never cross groups)
    part += __shfl_xor(part, 1);
    part += __shfl_xor(part, 2);
    part += __shfl_xor(part, 4);
    part += __shfl_xor(part, 8);
    float w = 1.0f + sc*tanh_fast(part + bb);
    w = valid ? w : 0.0f;
    float4 em0 = *(const float4*)(emp);
    float4 em1 = *(const float4*)(emp + 4);
    float4 em2 = *(const float4*)(emp + 8);
    float4 em3 = *(const float4*)(emp + 12);
    acc[0]  += w*(bf2f(g0[4]) + em0.x);
    acc[1]  += w*(bf2f(g0[5]) + em0.y);
    acc[2]  += w*(bf2f(g0[6]) + em0.z);
    acc[3]  += w*(bf2f(g0[7]) + em0.w);
    acc[4]  += w*(bf2f(g1[4]) + em1.x);
    acc[5]  += w*(bf2f(g1[5]) + em1.y);
    acc[6]  += w*(bf2f(g1[6]) + em1.z);
    acc[7]  += w*(bf2f(g1[7]) + em1.w);
    acc[8]  += w*(bf2f(g2[4]) + em2.x);
    acc[9]  += w*(bf2f(g2[5]) + em2.y);
    acc[10] += w*(bf2f(g2[6]) + em2.z);
    acc[11] += w*(bf2f(g2[7]) + em2.w);
    acc[12] += w*(bf2f(g3[4]) + em3.x);
    acc[13] += w*(bf2f(g3[5]) + em3.y);
    acc[14] += w*(bf2f(g3[6]) + em3.z);
    acc[15] += w*(bf2f(g3[7]) + em3.w);
    W += w;
  }

  // combine the 4 groups (lanes l, l+16, l+32, l+48 hold identical dims)
  #pragma unroll
  for (int j = 0; j < 16; ++j){
    acc[j] += __shfl_xor(acc[j], 16);
    acc[j] += __shfl_xor(acc[j], 32);
  }
  W += __shfl_xor(W, 16);
  W += __shfl_xor(W, 32);

  if (grp == 0){
    float d = fmaxf(W, 1.0f), rd = 1.0f / d;
    unsigned short st[16];
    #pragma unroll
    for (int c = 0; c < 4; ++c){
      float4 ms = *(const float4*)(tabs + TAB_MSG_SCALE + d0 + c*4);
      float4 mb = *(const float4*)(tabs + TAB_MSG_BETA  + d0 + c*4);
      float4 us = *(const float4*)(tabs + TAB_UPD_SCALE + d0 + c*4);
      float4 ub = *(const float4*)(tabs + TAB_UPD_BETA  + d0 + c*4);
      st[c*4+0] = f2bf((ms.x*acc[c*4+0] + mb.x*W)*rd*us.x + ub.x);
      st[c*4+1] = f2bf((ms.y*acc[c*4+1] + mb.y*W)*rd*us.y + ub.y);
      st[c*4+2] = f2bf((ms.z*acc[c*4+2] + mb.z*W)*rd*us.z + ub.z);
      st[c*4+3] = f2bf((ms.w*acc[c*4+3] + mb.w*W)*rd*us.w + ub.w);
    }
    unsigned short* up = updB + (size_t)node*256 + d0;
    *(u16x8*)(up)     = *(u16x8*)(st);
    *(u16x8*)(up + 8) = *(u16x8*)(st + 8);
  }
}

// ---------------- K4 v3: 32-row dense MLP + residual + in-register LayerNorm (proven) ----------------
__device__ __forceinline__ bf16x8 ldA(const float* xrow, const unsigned short* urow, int ke){
  if (ke < 256){
    float4 f0 = *(const float4*)(xrow + ke);
    float4 f1 = *(const float4*)(xrow + ke + 4);
    bf16x8 v;
    v[0]=(__bf16)f0.x; v[1]=(__bf16)f0.y; v[2]=(__bf16)f0.z; v[3]=(__bf16)f0.w;
    v[4]=(__bf16)f1.x; v[5]=(__bf16)f1.y; v[6]=(__bf16)f1.z; v[7]=(__bf16)f1.w;
    return v;
  }
  return *(const bf16x8*)(urow + (ke - 256));
}

__global__ __launch_bounds__(256) void k_mlp(
    const float* __restrict__ X, const unsigned short* __restrict__ updB,
    const unsigned short* __restrict__ W1T, const unsigned short* __restrict__ W2T,
    const float* __restrict__ up_b1, const float* __restrict__ up_b2,
    const float* __restrict__ ln_g, const float* __restrict__ ln_b,
    float* __restrict__ out)
{
  __shared__ __align__(16) unsigned short s_H[32*256]; // bf16, ^=(row&7)<<3
  __shared__ float s_sum[4*32], s_sq[4*32];
  __shared__ float s_mu[32], s_rs[32];
  int m0 = blockIdx.x*32;
  int tid = threadIdx.x;
  int wv = tid >> 6, lane = tid & 63, lo = lane & 15, hi = lane >> 4;

  const float* x0 = X + (size_t)(m0 + lo)*256;
  const float* x1 = x0 + 16*256;
  const unsigned short* u0 = updB + (size_t)(m0 + lo)*256;
  const unsigned short* u1 = u0 + 16*256;

  f32x4 acc0[4], acc1[4];
  #pragma unroll
  for (int t = 0; t < 4; ++t){
    float b = up_b1[wv*64 + t*16 + lo];
    acc0[t] = (f32x4){b, b, b, b};
    acc1[t] = acc0[t];
  }
  #pragma unroll
  for (int kc = 0; kc < 16; ++kc){
    int ke = kc*32 + hi*8;
    bf16x8 a0 = ldA(x0, u0, ke);
    bf16x8 a1 = ldA(x1, u1, ke);
    #pragma unroll
    for (int t = 0; t < 4; ++t){
      int n = wv*64 + t*16 + lo;
      bf16x8 bf = *(const bf16x8*)(W1T + (size_t)n*512 + ke);
      acc0[t] = __builtin_amdgcn_mfma_f32_16x16x32_bf16(a0, bf, acc0[t], 0, 0, 0);
      acc1[t] = __builtin_amdgcn_mfma_f32_16x16x32_bf16(a1, bf, acc1[t], 0, 0, 0);
    }
  }
  #pragma unroll
  for (int t = 0; t < 4; ++t){
    #pragma unroll
    for (int r = 0; r < 4; ++r){
      int row0 = hi*4 + r, n = wv*64 + t*16 + lo;
      s_H[(row0 << 8) | (n ^ ((row0 & 7) << 3))] = f2bf(gelu_fast(acc0[t][r]));
      int row1 = row0 + 16;
      s_H[(row1 << 8) | (n ^ ((row1 & 7) << 3))] = f2bf(gelu_fast(acc1[t][r]));
    }
  }
  __syncthreads();

  f32x4 y0[4], y1[4];
  #pragma unroll
  for (int t = 0; t < 4; ++t){
    float b = up_b2[wv*64 + t*16 + lo];
    y0[t] = (f32x4){b, b, b, b};
    y1[t] = y0[t];
  }
  #pragma unroll
  for (int kc = 0; kc < 8; ++kc){
    int ke = kc*32 + hi*8;
    bf16x8 af0 = *(const bf16x8*)(s_H + ((lo << 8) | (ke ^ ((lo & 7) << 3))));
    int r1 = lo + 16;
    bf16x8 af1 = *(const bf16x8*)(s_H + ((r1 << 8) | (ke ^ ((r1 & 7) << 3))));
    #pragma unroll
    for (int t = 0; t < 4; ++t){
      int n = wv*64 + t*16 + lo;
      bf16x8 bf = *(const bf16x8*)(W2T + (size_t)n*256 + ke);
      y0[t] = __builtin_amdgcn_mfma_f32_16x16x32_bf16(af0, bf, y0[t], 0, 0, 0);
      y1[t] = __builtin_amdgcn_mfma_f32_16x16x32_bf16(af1, bf, y1[t], 0, 0, 0);
    }
  }

  #pragma unroll
  for (int t = 0; t < 4; ++t){
    #pragma unroll
    for (int r = 0; r < 4; ++r){
      int row0 = hi*4 + r, n = wv*64 + t*16 + lo;
      y0[t][r] += X[(size_t)(m0 + row0)*256 + n];
      y1[t][r] += X[(size_t)(m0 + row0 + 16)*256 + n];
    }
  }

  float ps[2][4], pq[2][4];
  #pragma unroll
  for (int r = 0; r < 4; ++r){
    float s0 = 0.f, q0 = 0.f, s1 = 0.f, q1 = 0.f;
    #pragma unroll
    for (int t = 0; t < 4; ++t){
      s0 += y0[t][r]; q0 += y0[t][r]*y0[t][r];
      s1 += y1[t][r]; q1 += y1[t][r]*y1[t][r];
    }
    #pragma unroll
    for (int off = 1; off < 16; off <<= 1){
      s0 += __shfl_xor(s0, off); q0 += __shfl_xor(q0, off);
      s1 += __shfl_xor(s1, off); q1 += __shfl_xor(q1, off);
    }
    ps[0][r] = s0; pq[0][r] = q0;
    ps[1][r] = s1; pq[1][r] = q1;
  }
  if (lo == 0){
    #pragma unroll
    for (int m = 0; m < 2; ++m){
      #pragma unroll
      for (int r = 0; r < 4; ++r){
        int row = m*16 + hi*4 + r;
        s_sum[wv*32 + row] = ps[m][r];
        s_sq [wv*32 + row] = pq[m][r];
      }
    }
  }
  __syncthreads();
  if (tid < 32){
    float sum = s_sum[tid] + s_sum[32 + tid] + s_sum[64 + tid] + s_sum[96 + tid];
    float sq  = s_sq[tid]  + s_sq[32 + tid]  + s_sq[64 + tid]  + s_sq[96 + tid];
    float mu = sum * (1.0f/256.0f);
    float var = sq * (1.0f/256.0f) - mu*mu;
    s_mu[tid] = mu;
    s_rs[tid] = rsqrtf(var + 1e-5f);
  }
  __syncthreads();

  #pragma unroll
  for (int t = 0; t < 4; ++t){
    int n = wv*64 + t*16 + lo;
    float lg = ln_g[n], lb = ln_b[n];
    #pragma unroll
    for (int r = 0; r < 4; ++r){
      int row0 = hi*4 + r, row1 = row0 + 16;
      out[(size_t)(m0 + row0)*256 + n] = (y0[t][r] - s_mu[row0]) * s_rs[row0] * lg + lb;
      out[(size_t)(m0 + row1)*256 + n] = (y1[t][r] - s_mu[row1]) * s_rs[row1] * lg + lb;
    }
  }
}

extern "C" void kernel_launch(void* const* d_in, const int* in_sizes, int n_in,
                              void* d_out, int out_size, void* d_ws, size_t ws_size,
                              hipStream_t stream)
{
  (void)in_sizes; (void)n_in; (void)out_size;
  if (ws_size < WS_NEED) return;
  const float* X      = (const float*)d_in[0];
  const int*   eidx   = (const int*)d_in[1];
  const int*   etype  = (const int*)d_in[2];
  const float* task   = (const float*)d_in[3];
  const float* eemb   = (const float*)d_in[4];
  const float* msg_W  = (const float*)d_in[5];
  const float* msg_b  = (const float*)d_in[6];
  const float* att_W1 = (const float*)d_in[7];
  const float* att_b1 = (const float*)d_in[8];
  const float* att_W2 = (const float*)d_in[9];
  const float* att_b2 = (const float*)d_in[10];
  const float* escale = (const float*)d_in[11];
  const float* ma_W1  = (const float*)d_in[12];
  const float* ma_b1  = (const float*)d_in[13];
  const float* ma_W2  = (const float*)d_in[14];
  const float* ma_b2  = (const float*)d_in[15];
  const float* up_W1  = (const float*)d_in[16];
  const float* up_b1  = (const float*)d_in[17];
  const float* up_W2  = (const float*)d_in[18];
  const float* up_b2  = (const float*)d_in[19];
  const float* ua_W1  = (const float*)d_in[20];
  const float* ua_b1  = (const float*)d_in[21];
  const float* ua_W2  = (const float*)d_in[22];
  const float* ua_b2  = (const float*)d_in[23];
  const float* ln_g   = (const float*)d_in[24];
  const float* ln_b   = (const float*)d_in[25];
  char* ws = (char*)d_ws;
  float* tabs = (float*)ws;
  unsigned short* WpreT = (unsigned short*)(ws + OFF_WPRET);
  unsigned short* W1T   = (unsigned short*)(ws + OFF_W1T);
  unsigned short* W2T   = (unsigned short*)(ws + OFF_W2T);
  int*          cnt   = (int*)(ws + OFF_CNT);
  int*          ptrs  = (int*)(ws + OFF_PTRS);
  int*          pwork = (int*)(ws + OFF_PWORK);
  unsigned int* srcet = (unsigned int*)(ws + OFF_SRCET);
  unsigned short* updB = (unsigned short*)(ws + OFF_UPDB);
  unsigned short* G    = (unsigned short*)(ws + OFF_G);
  unsigned short* P2b  = (unsigned short*)(ws + OFF_P2B);
  float* out = (float*)d_out;

  hipMemsetAsync(cnt, 0, (size_t)NN*4, stream);
  k_tables<<<35, 256, 0, stream>>>(task, eemb, msg_W, msg_b, att_W1, att_b1,
                                   ma_W1, ma_b1, ma_W2, ma_b2,
                                   ua_W1, ua_b1, ua_W2, ua_b2, tabs);
  k_prep<<<1280, 256, 0, stream>>>(msg_W, att_W1, up_W1, up_W2, WpreT, W1T, W2T);
  k_gemm_pre<<<(NN + 63)/64, 256, 0, stream>>>(X, WpreT, tabs, G, P2b);
  k_hist<<<(NE + 255)/256, 256, 0, stream>>>(eidx, cnt);
  k_scan<<<1, 1024, 0, stream>>>(cnt, ptrs, pwork);
  k_csr_build<<<(NE + 255)/256, 256, 0, stream>>>(eidx, etype, pwork, srcet);
  k_agg<<<(NN + 3)/4, 256, 0, stream>>>(ptrs, srcet, G, P2b, tabs,
                                        att_W2, att_b2, escale, updB);
  k_mlp<<<NN/32, 256, 0, stream>>>(X, updB, W1T, W2T, up_b1, up_b2,
                                   ln_g, ln_b, out);
}

// Round 9
// 255.113 us; speedup vs baseline: 1.1245x; 1.1245x over previous
//
#include <hip/hip_runtime.h>
#include <hip/hip_bf16.h>

#define NN 20000
#define NE 200000

typedef __bf16 bf16x8 __attribute__((ext_vector_type(8)));
typedef float f32x4 __attribute__((ext_vector_type(4)));
typedef unsigned short u16x8 __attribute__((ext_vector_type(8)));

// ---- workspace layout (bytes) ----
constexpr int TAB_MSG_SCALE = 0;      // f32 element offsets within tabs
constexpr int TAB_MSG_BETA  = 256;
constexpr int TAB_UPD_SCALE = 512;
constexpr int TAB_UPD_BETA  = 768;
constexpr int TAB_TASKC     = 1024;   // task @ att_W1[768:1024] + att_b1
constexpr int TAB_EM        = 1280;   // 16*256  e@msg_W + msg_b
constexpr int TAB_EC        = 1280 + 4096; // 16*256  e@att_W1[512:768]
constexpr size_t OFF_WPRET = 40960;    // u16[768*256] n-major
constexpr size_t OFF_W1T   = 434176;   // u16[256*512]
constexpr size_t OFF_W2T   = 696320;   // u16[256*256]
constexpr size_t OFF_CNT   = 827392;   // i32[NN]
constexpr size_t OFF_PTRS  = 907392;   // i32[NN+1]
constexpr size_t OFF_PWORK = 987648;   // i32[NN]
constexpr size_t OFF_SRCET = 1067648;  // u32[NE]  src | et<<16 (CSR order)
constexpr size_t OFF_UPDB  = 1867648;  // u16[NN*256]  aggregated+modulated upd half (bf16)
constexpr size_t OFF_G     = 12107648; // u16[NN*512]  interleaved [P1|M] per 4-dim group
constexpr size_t OFF_P2B   = 32587648; // u16[NN*256]  P2 + taskc (bf16)
constexpr size_t WS_NEED   = 42827648;

__device__ __forceinline__ float bf2f(unsigned short u){
  union { unsigned int i; float f; } v; v.i = ((unsigned int)u) << 16; return v.f;
}
__device__ __forceinline__ unsigned short f2bf(float f){
  __bf16 h = (__bf16)f; unsigned short u; __builtin_memcpy(&u, &h, 2); return u;
}
__device__ __forceinline__ float gelu_f(float x){
  return 0.5f * x * (1.0f + erff(x * 0.70710678118654752f));
}
// fast sigmoid-gelu: max abs err ~0.01 vs exact
__device__ __forceinline__ float gelu_fast(float x){
  return x / (1.0f + __expf(-1.702f * x));
}
// overflow-safe fast tanh
__device__ __forceinline__ float tanh_fast(float x){
  float e = __expf(2.0f * x);
  return 1.0f - 2.0f / (e + 1.0f);
}

// ---------------- K_setup: fused tables + weight transposes + degree histogram ----------------
// blocks [0,35): tables; [35,1315): prep; [1315,2097): hist. All independent.
__global__ __launch_bounds__(256) void k_setup(
    const float* __restrict__ task, const float* __restrict__ eemb,
    const float* __restrict__ msg_W, const float* __restrict__ msg_b,
    const float* __restrict__ att_W1, const float* __restrict__ att_b1,
    const float* __restrict__ ma_W1, const float* __restrict__ ma_b1,
    const float* __restrict__ ma_W2, const float* __restrict__ ma_b2,
    const float* __restrict__ ua_W1, const float* __restrict__ ua_b1,
    const float* __restrict__ ua_W2, const float* __restrict__ ua_b2,
    const float* __restrict__ up_W1, const float* __restrict__ up_W2,
    const int* __restrict__ eidx,
    float* __restrict__ tabs,
    unsigned short* __restrict__ WpreT, unsigned short* __restrict__ W1T,
    unsigned short* __restrict__ W2T, int* __restrict__ cnt)
{
  __shared__ float s_in[512];
  __shared__ float s_h[512];
  int bb = blockIdx.x, tid = threadIdx.x;
  if (bb >= 1315){
    int e = (bb - 1315)*256 + tid;
    if (e < NE) atomicAdd(&cnt[eidx[NE + e]], 1);
    return;
  }
  if (bb >= 35){
    int b = bb - 35;
    if (b < 768){
      int n = b;
      float v;
      if (n < 256)      v = msg_W[tid*256 + n];
      else if (n < 512) v = att_W1[tid*256 + (n - 256)];
      else              v = att_W1[(256 + tid)*256 + (n - 512)];
      WpreT[n*256 + tid] = f2bf(v);
    } else if (b < 1024){
      int n = b - 768;
      W1T[n*512 + tid]       = f2bf(up_W1[tid*256 + n]);
      W1T[n*512 + 256 + tid] = f2bf(up_W1[(256 + tid)*256 + n]);
    } else {
      int n = b - 1024;
      W2T[n*256 + tid] = f2bf(up_W2[tid*256 + n]);
    }
    return;
  }
  int b = bb;
  if (b < 2){
    const float* W1 = b ? ua_W1 : ma_W1;  const float* b1 = b ? ua_b1 : ma_b1;
    const float* W2 = b ? ua_W2 : ma_W2;  const float* b2 = b ? ua_b2 : ma_b2;
    s_in[tid] = task[tid];
    __syncthreads();
    #pragma unroll
    for (int jj = 0; jj < 2; ++jj){
      int j = tid + jj*256;
      float acc = b1[j];
      for (int k = 0; k < 256; ++k) acc += s_in[k] * W1[k*512 + j];
      s_h[j] = gelu_f(acc);
    }
    __syncthreads();
    float o[2];
    #pragma unroll
    for (int jj = 0; jj < 2; ++jj){
      int j = tid + jj*256;
      float acc = b2[j];
      for (int k = 0; k < 512; ++k) acc += s_h[k] * W2[k*512 + j];
      o[jj] = acc;
    }
    float* scale = tabs + (b ? TAB_UPD_SCALE : TAB_MSG_SCALE);
    float* beta  = tabs + (b ? TAB_UPD_BETA  : TAB_MSG_BETA);
    scale[tid] = 1.0f + 0.5f * tanhf(o[0]);
    beta[tid]  = o[1];
  } else if (b == 2){
    s_in[tid] = task[tid];
    __syncthreads();
    float acc = att_b1[tid];
    for (int k = 0; k < 256; ++k) acc += s_in[k] * att_W1[(768 + k)*256 + tid];
    tabs[TAB_TASKC + tid] = acc;
  } else if (b < 19){
    int t = b - 3;
    s_in[tid] = eemb[t*256 + tid];
    __syncthreads();
    float acc = msg_b[tid];
    for (int k = 0; k < 256; ++k) acc += s_in[k] * msg_W[k*256 + tid];
    tabs[TAB_EM + t*256 + tid] = acc;
  } else {
    int t = b - 19;
    s_in[tid] = eemb[t*256 + tid];
    __syncthreads();
    float acc = 0.f;
    for (int k = 0; k < 256; ++k) acc += s_in[k] * att_W1[(512 + k)*256 + tid];
    tabs[TAB_EC + t*256 + tid] = acc;
  }
}

// ---------------- K1: G=[P1|M interleaved], P2b (proven) ----------------
__global__ __launch_bounds__(256) void k_gemm_pre(
    const float* __restrict__ X, const unsigned short* __restrict__ WpreT,
    const float* __restrict__ tabs,
    unsigned short* __restrict__ G, unsigned short* __restrict__ P2b)
{
  __shared__ __align__(16) unsigned short s_b[16*256]; // 8KB, swizzled elem ^= (n&7)<<3
  int tid = threadIdx.x, wv = tid >> 6, lane = tid & 63;
  int m0 = blockIdx.x*64 + wv*16;
  bool valid = (m0 < NN);
  int lo = lane & 15, hi = lane >> 4;
  bf16x8 a[8];
  if (valid){
    const float* xrow = X + (size_t)(m0 + lo)*256 + hi*8;
    #pragma unroll
    for (int kc = 0; kc < 8; ++kc){
      float4 f0 = *(const float4*)(xrow + kc*32);
      float4 f1 = *(const float4*)(xrow + kc*32 + 4);
      bf16x8 v;
      v[0]=(__bf16)f0.x; v[1]=(__bf16)f0.y; v[2]=(__bf16)f0.z; v[3]=(__bf16)f0.w;
      v[4]=(__bf16)f1.x; v[5]=(__bf16)f1.y; v[6]=(__bf16)f1.z; v[7]=(__bf16)f1.w;
      a[kc] = v;
    }
  }
  int sn = tid >> 4, sk0 = (tid & 15)*16;
  int sswz = (sn & 7) << 3;
  int rswz = (lo & 7) << 3;
  for (int nt = 0; nt < 48; ++nt){
    __syncthreads();
    {
      const unsigned short* gsrc = WpreT + (size_t)(nt*16 + sn)*256 + sk0;
      uint4 d0 = *(const uint4*)(gsrc);
      uint4 d1 = *(const uint4*)(gsrc + 8);
      *(uint4*)(s_b + sn*256 + (sk0 ^ sswz))       = d0;
      *(uint4*)(s_b + sn*256 + ((sk0 + 8) ^ sswz)) = d1;
    }
    __syncthreads();
    if (!valid) continue;
    f32x4 acc = {0.f, 0.f, 0.f, 0.f};
    #pragma unroll
    for (int kc = 0; kc < 8; ++kc){
      bf16x8 bfrag = *(const bf16x8*)(s_b + lo*256 + ((kc*32 + hi*8) ^ rswz));
      acc = __builtin_amdgcn_mfma_f32_16x16x32_bf16(a[kc], bfrag, acc, 0, 0, 0);
    }
    int n0 = nt*16;
    if (nt < 16){
      int j = n0 + lo;
      int elem = ((j >> 2) << 3) + 4 + (j & 3);
      unsigned short* grow = G + (size_t)(m0 + hi*4)*512 + elem;
      #pragma unroll
      for (int r = 0; r < 4; ++r) grow[(size_t)r*512] = f2bf(acc[r]);
    } else if (nt < 32){
      int j = n0 - 256 + lo;
      int elem = ((j >> 2) << 3) + (j & 3);
      unsigned short* grow = G + (size_t)(m0 + hi*4)*512 + elem;
      #pragma unroll
      for (int r = 0; r < 4; ++r) grow[(size_t)r*512] = f2bf(acc[r]);
    } else {
      int j = n0 - 512 + lo;
      float tcadd = tabs[TAB_TASKC + j];
      unsigned short* prow = P2b + (size_t)(m0 + hi*4)*256 + j;
      #pragma unroll
      for (int r = 0; r < 4; ++r) prow[(size_t)r*256] = f2bf(acc[r] + tcadd);
    }
  }
}

// ---------------- K2b: exclusive prefix sum (1 block, 20 elems/thread) ----------------
__global__ __launch_bounds__(1024) void k_scan(
    const int* __restrict__ cnt, int* __restrict__ ptrs, int* __restrict__ pwork)
{
  __shared__ int s[1024];
  int tid = threadIdx.x;
  int loc[20];
  int tot = 0;
  #pragma unroll
  for (int j = 0; j < 20; ++j){
    int i = tid*20 + j;
    loc[j] = tot;
    tot += (i < NN) ? cnt[i] : 0;
  }
  s[tid] = tot;
  __syncthreads();
  #pragma unroll
  for (int off = 1; off < 1024; off <<= 1){
    int t = (tid >= off) ? s[tid - off] : 0;
    __syncthreads();
    s[tid] += t;
    __syncthreads();
  }
  int base = s[tid] - tot;
  #pragma unroll
  for (int j = 0; j < 20; ++j){
    int i = tid*20 + j;
    if (i < NN){
      ptrs[i]  = base + loc[j];
      pwork[i] = base + loc[j];
    }
  }
  if (tid == 1023) ptrs[NN] = s[1023];
}

// ---------------- K2c: CSR build ----------------
__global__ __launch_bounds__(256) void k_csr_build(
    const int* __restrict__ eidx, const int* __restrict__ etype,
    int* __restrict__ pwork, unsigned int* __restrict__ srcet)
{
  int e = blockIdx.x*256 + threadIdx.x;
  if (e < NE){
    int dst = eidx[NE + e];
    int pos = atomicAdd(&pwork[dst], 1);
    srcet[pos] = (unsigned int)eidx[e] | ((unsigned int)etype[e] << 16);
  }
}

// ---------------- K3: fused attention + aggregate (proven round-6: 1 wave/node) ----------------
__global__ __launch_bounds__(256) void k_agg(
    const int* __restrict__ ptrs, const unsigned int* __restrict__ srcet,
    const unsigned short* __restrict__ G, const unsigned short* __restrict__ P2b,
    const float* __restrict__ tabs, const float* __restrict__ attW2,
    const float* __restrict__ attb2, const float* __restrict__ escale,
    unsigned short* __restrict__ updB)
{
  int node = blockIdx.x*4 + (threadIdx.x >> 6);
  if (node >= NN) return;
  int lane = threadIdx.x & 63, c0 = lane*4;
  ushort4 p2 = *(const ushort4*)(P2b + (size_t)node*256 + c0);
  float q0 = bf2f(p2.x), q1 = bf2f(p2.y), q2 = bf2f(p2.z), q3 = bf2f(p2.w);
  float4 w2 = *(const float4*)(attW2 + c0);
  float sc = escale[0], bb = attb2[0];
  float4 ms = *(const float4*)(tabs + TAB_MSG_SCALE + c0);
  float4 mb = *(const float4*)(tabs + TAB_MSG_BETA  + c0);
  float4 us = *(const float4*)(tabs + TAB_UPD_SCALE + c0);
  float4 ub = *(const float4*)(tabs + TAB_UPD_BETA  + c0);
  int start = ptrs[node], end = ptrs[node + 1];
  float ax = 0.f, ay = 0.f, az = 0.f, aw = 0.f, W = 0.f;
  unsigned int se0 = 0, se1 = 0;
  u16x8 g0 = {0,0,0,0,0,0,0,0};
  if (start < end){
    se0 = srcet[start];
    g0 = *(const u16x8*)(G + (size_t)(se0 & 0xFFFFu)*512 + lane*8);
    if (start + 1 < end) se1 = srcet[start + 1];
  }
  for (int i = start; i < end; ++i){
    u16x8 g1 = g0;
    unsigned int se2 = 0;
    if (i + 1 < end) g1 = *(const u16x8*)(G + (size_t)(se1 & 0xFFFFu)*512 + lane*8);
    if (i + 2 < end) se2 = srcet[i + 2];
    int et = (int)(se0 >> 16);
    float4 ec = *(const float4*)(tabs + TAB_EC + et*256 + c0);
    float part = gelu_fast(bf2f(g0[0]) + q0 + ec.x)*w2.x
               + gelu_fast(bf2f(g0[1]) + q1 + ec.y)*w2.y
               + gelu_fast(bf2f(g0[2]) + q2 + ec.z)*w2.z
               + gelu_fast(bf2f(g0[3]) + q3 + ec.w)*w2.w;
    #pragma unroll
    for (int off = 32; off; off >>= 1) part += __shfl_xor(part, off);
    float w = 1.0f + sc*tanh_fast(part + bb);
    float4 em = *(const float4*)(tabs + TAB_EM + et*256 + c0);
    ax += w*(bf2f(g0[4]) + em.x);
    ay += w*(bf2f(g0[5]) + em.y);
    az += w*(bf2f(g0[6]) + em.z);
    aw += w*(bf2f(g0[7]) + em.w);
    W += w;
    se0 = se1; se1 = se2; g0 = g1;
  }
  float d = fmaxf(W, 1.0f), rd = 1.0f / d;
  ushort4 st = { f2bf((ms.x*ax + mb.x*W)*rd*us.x + ub.x),
                 f2bf((ms.y*ay + mb.y*W)*rd*us.y + ub.y),
                 f2bf((ms.z*az + mb.z*W)*rd*us.z + ub.z),
                 f2bf((ms.w*aw + mb.w*W)*rd*us.w + ub.w) };
  *(ushort4*)(updB + (size_t)node*256 + c0) = st;
}

// ---------------- K4: 32-row dense MLP + residual + in-register LayerNorm (proven) ----------------
__device__ __forceinline__ bf16x8 ldA(const float* xrow, const unsigned short* urow, int ke){
  if (ke < 256){
    float4 f0 = *(const float4*)(xrow + ke);
    float4 f1 = *(const float4*)(xrow + ke + 4);
    bf16x8 v;
    v[0]=(__bf16)f0.x; v[1]=(__bf16)f0.y; v[2]=(__bf16)f0.z; v[3]=(__bf16)f0.w;
    v[4]=(__bf16)f1.x; v[5]=(__bf16)f1.y; v[6]=(__bf16)f1.z; v[7]=(__bf16)f1.w;
    return v;
  }
  return *(const bf16x8*)(urow + (ke - 256));
}

__global__ __launch_bounds__(256) void k_mlp(
    const float* __restrict__ X, const unsigned short* __restrict__ updB,
    const unsigned short* __restrict__ W1T, const unsigned short* __restrict__ W2T,
    const float* __restrict__ up_b1, const float* __restrict__ up_b2,
    const float* __restrict__ ln_g, const float* __restrict__ ln_b,
    float* __restrict__ out)
{
  __shared__ __align__(16) unsigned short s_H[32*256]; // bf16, ^=(row&7)<<3
  __shared__ float s_sum[4*32], s_sq[4*32];
  __shared__ float s_mu[32], s_rs[32];
  int m0 = blockIdx.x*32;
  int tid = threadIdx.x;
  int wv = tid >> 6, lane = tid & 63, lo = lane & 15, hi = lane >> 4;

  const float* x0 = X + (size_t)(m0 + lo)*256;
  const float* x1 = x0 + 16*256;
  const unsigned short* u0 = updB + (size_t)(m0 + lo)*256;
  const unsigned short* u1 = u0 + 16*256;

  f32x4 acc0[4], acc1[4];
  #pragma unroll
  for (int t = 0; t < 4; ++t){
    float b = up_b1[wv*64 + t*16 + lo];
    acc0[t] = (f32x4){b, b, b, b};
    acc1[t] = acc0[t];
  }
  #pragma unroll
  for (int kc = 0; kc < 16; ++kc){
    int ke = kc*32 + hi*8;
    bf16x8 a0 = ldA(x0, u0, ke);
    bf16x8 a1 = ldA(x1, u1, ke);
    #pragma unroll
    for (int t = 0; t < 4; ++t){
      int n = wv*64 + t*16 + lo;
      bf16x8 bf = *(const bf16x8*)(W1T + (size_t)n*512 + ke);
      acc0[t] = __builtin_amdgcn_mfma_f32_16x16x32_bf16(a0, bf, acc0[t], 0, 0, 0);
      acc1[t] = __builtin_amdgcn_mfma_f32_16x16x32_bf16(a1, bf, acc1[t], 0, 0, 0);
    }
  }
  #pragma unroll
  for (int t = 0; t < 4; ++t){
    #pragma unroll
    for (int r = 0; r < 4; ++r){
      int row0 = hi*4 + r, n = wv*64 + t*16 + lo;
      s_H[(row0 << 8) | (n ^ ((row0 & 7) << 3))] = f2bf(gelu_fast(acc0[t][r]));
      int row1 = row0 + 16;
      s_H[(row1 << 8) | (n ^ ((row1 & 7) << 3))] = f2bf(gelu_fast(acc1[t][r]));
    }
  }
  __syncthreads();

  f32x4 y0[4], y1[4];
  #pragma unroll
  for (int t = 0; t < 4; ++t){
    float b = up_b2[wv*64 + t*16 + lo];
    y0[t] = (f32x4){b, b, b, b};
    y1[t] = y0[t];
  }
  #pragma unroll
  for (int kc = 0; kc < 8; ++kc){
    int ke = kc*32 + hi*8;
    bf16x8 af0 = *(const bf16x8*)(s_H + ((lo << 8) | (ke ^ ((lo & 7) << 3))));
    int r1 = lo + 16;
    bf16x8 af1 = *(const bf16x8*)(s_H + ((r1 << 8) | (ke ^ ((r1 & 7) << 3))));
    #pragma unroll
    for (int t = 0; t < 4; ++t){
      int n = wv*64 + t*16 + lo;
      bf16x8 bf = *(const bf16x8*)(W2T + (size_t)n*256 + ke);
      y0[t] = __builtin_amdgcn_mfma_f32_16x16x32_bf16(af0, bf, y0[t], 0, 0, 0);
      y1[t] = __builtin_amdgcn_mfma_f32_16x16x32_bf16(af1, bf, y1[t], 0, 0, 0);
    }
  }

  #pragma unroll
  for (int t = 0; t < 4; ++t){
    #pragma unroll
    for (int r = 0; r < 4; ++r){
      int row0 = hi*4 + r, n = wv*64 + t*16 + lo;
      y0[t][r] += X[(size_t)(m0 + row0)*256 + n];
      y1[t][r] += X[(size_t)(m0 + row0 + 16)*256 + n];
    }
  }

  float ps[2][4], pq[2][4];
  #pragma unroll
  for (int r = 0; r < 4; ++r){
    float s0 = 0.f, q0 = 0.f, s1 = 0.f, q1 = 0.f;
    #pragma unroll
    for (int t = 0; t < 4; ++t){
      s0 += y0[t][r]; q0 += y0[t][r]*y0[t][r];
      s1 += y1[t][r]; q1 += y1[t][r]*y1[t][r];
    }
    #pragma unroll
    for (int off = 1; off < 16; off <<= 1){
      s0 += __shfl_xor(s0, off); q0 += __shfl_xor(q0, off);
      s1 += __shfl_xor(s1, off); q1 += __shfl_xor(q1, off);
    }
    ps[0][r] = s0; pq[0][r] = q0;
    ps[1][r] = s1; pq[1][r] = q1;
  }
  if (lo == 0){
    #pragma unroll
    for (int m = 0; m < 2; ++m){
      #pragma unroll
      for (int r = 0; r < 4; ++r){
        int row = m*16 + hi*4 + r;
        s_sum[wv*32 + row] = ps[m][r];
        s_sq [wv*32 + row] = pq[m][r];
      }
    }
  }
  __syncthreads();
  if (tid < 32){
    float sum = s_sum[tid] + s_sum[32 + tid] + s_sum[64 + tid] + s_sum[96 + tid];
    float sq  = s_sq[tid]  + s_sq[32 + tid]  + s_sq[64 + tid]  + s_sq[96 + tid];
    float mu = sum * (1.0f/256.0f);
    float var = sq * (1.0f/256.0f) - mu*mu;
    s_mu[tid] = mu;
    s_rs[tid] = rsqrtf(var + 1e-5f);
  }
  __syncthreads();

  #pragma unroll
  for (int t = 0; t < 4; ++t){
    int n = wv*64 + t*16 + lo;
    float lg = ln_g[n], lb = ln_b[n];
    #pragma unroll
    for (int r = 0; r < 4; ++r){
      int row0 = hi*4 + r, row1 = row0 + 16;
      out[(size_t)(m0 + row0)*256 + n] = (y0[t][r] - s_mu[row0]) * s_rs[row0] * lg + lb;
      out[(size_t)(m0 + row1)*256 + n] = (y1[t][r] - s_mu[row1]) * s_rs[row1] * lg + lb;
    }
  }
}

extern "C" void kernel_launch(void* const* d_in, const int* in_sizes, int n_in,
                              void* d_out, int out_size, void* d_ws, size_t ws_size,
                              hipStream_t stream)
{
  (void)in_sizes; (void)n_in; (void)out_size;
  if (ws_size < WS_NEED) return;
  const float* X      = (const float*)d_in[0];
  const int*   eidx   = (const int*)d_in[1];
  const int*   etype  = (const int*)d_in[2];
  const float* task   = (const float*)d_in[3];
  const float* eemb   = (const float*)d_in[4];
  const float* msg_W  = (const float*)d_in[5];
  const float* msg_b  = (const float*)d_in[6];
  const float* att_W1 = (const float*)d_in[7];
  const float* att_b1 = (const float*)d_in[8];
  const float* att_W2 = (const float*)d_in[9];
  const float* att_b2 = (const float*)d_in[10];
  const float* escale = (const float*)d_in[11];
  const float* ma_W1  = (const float*)d_in[12];
  const float* ma_b1  = (const float*)d_in[13];
  const float* ma_W2  = (const float*)d_in[14];
  const float* ma_b2  = (const float*)d_in[15];
  const float* up_W1  = (const float*)d_in[16];
  const float* up_b1  = (const float*)d_in[17];
  const float* up_W2  = (const float*)d_in[18];
  const float* up_b2  = (const float*)d_in[19];
  const float* ua_W1  = (const float*)d_in[20];
  const float* ua_b1  = (const float*)d_in[21];
  const float* ua_W2  = (const float*)d_in[22];
  const float* ua_b2  = (const float*)d_in[23];
  const float* ln_g   = (const float*)d_in[24];
  const float* ln_b   = (const float*)d_in[25];
  char* ws = (char*)d_ws;
  float* tabs = (float*)ws;
  unsigned short* WpreT = (unsigned short*)(ws + OFF_WPRET);
  unsigned short* W1T   = (unsigned short*)(ws + OFF_W1T);
  unsigned short* W2T   = (unsigned short*)(ws + OFF_W2T);
  int*          cnt   = (int*)(ws + OFF_CNT);
  int*          ptrs  = (int*)(ws + OFF_PTRS);
  int*          pwork = (int*)(ws + OFF_PWORK);
  unsigned int* srcet = (unsigned int*)(ws + OFF_SRCET);
  unsigned short* updB = (unsigned short*)(ws + OFF_UPDB);
  unsigned short* G    = (unsigned short*)(ws + OFF_G);
  unsigned short* P2b  = (unsigned short*)(ws + OFF_P2B);
  float* out = (float*)d_out;

  hipMemsetAsync(cnt, 0, (size_t)NN*4, stream);
  k_setup<<<2097, 256, 0, stream>>>(task, eemb, msg_W, msg_b, att_W1, att_b1,
                                    ma_W1, ma_b1, ma_W2, ma_b2,
                                    ua_W1, ua_b1, ua_W2, ua_b2,
                                    up_W1, up_W2, eidx,
                                    tabs, WpreT, W1T, W2T, cnt);
  k_gemm_pre<<<(NN + 63)/64, 256, 0, stream>>>(X, WpreT, tabs, G, P2b);
  k_scan<<<1, 1024, 0, stream>>>(cnt, ptrs, pwork);
  k_csr_build<<<(NE + 255)/256, 256, 0, stream>>>(eidx, etype, pwork, srcet);
  k_agg<<<(NN + 3)/4, 256, 0, stream>>>(ptrs, srcet, G, P2b, tabs,
                                        att_W2, att_b2, escale, updB);
  k_mlp<<<NN/32, 256, 0, stream>>>(X, updB, W1T, W2T, up_b1, up_b2,
                                   ln_g, ln_b, out);
}

// Round 10
// 254.931 us; speedup vs baseline: 1.1253x; 1.0007x over previous
//
#include <hip/hip_runtime.h>
#include <hip/hip_bf16.h>

#define NN 20000
#define NE 200000

typedef __bf16 bf16x8 __attribute__((ext_vector_type(8)));
typedef float f32x4 __attribute__((ext_vector_type(4)));
typedef unsigned short u16x8 __attribute__((ext_vector_type(8)));

// ---- workspace layout (bytes) ----
constexpr int TAB_MSG_SCALE = 0;      // f32 element offsets within tabs
constexpr int TAB_MSG_BETA  = 256;
constexpr int TAB_UPD_SCALE = 512;
constexpr int TAB_UPD_BETA  = 768;
constexpr int TAB_TASKC     = 1024;   // task @ att_W1[768:1024] + att_b1
constexpr int TAB_EM        = 1280;   // 16*256  e@msg_W + msg_b
constexpr int TAB_EC        = 1280 + 4096; // 16*256  e@att_W1[512:768]
constexpr size_t OFF_WPRET = 40960;    // u16[768*256] n-major
constexpr size_t OFF_W1T   = 434176;   // u16[256*512]
constexpr size_t OFF_W2T   = 696320;   // u16[256*256]
constexpr size_t OFF_CNT   = 827392;   // i32[NN]
constexpr size_t OFF_PTRS  = 907392;   // i32[NN+1]
constexpr size_t OFF_PWORK = 987648;   // i32[NN]
constexpr size_t OFF_SRCET = 1067648;  // u32[NE]  src | et<<16 (CSR order)
constexpr size_t OFF_UPDB  = 1867648;  // u16[NN*256]  aggregated+modulated upd half (bf16)
constexpr size_t OFF_G     = 12107648; // u16[NN*512]  interleaved [P1|M] per 4-dim group
constexpr size_t OFF_P2B   = 32587648; // u16[NN*256]  P2 + taskc (bf16)
constexpr size_t WS_NEED   = 42827648;

__device__ __forceinline__ float bf2f(unsigned short u){
  union { unsigned int i; float f; } v; v.i = ((unsigned int)u) << 16; return v.f;
}
__device__ __forceinline__ unsigned short f2bf(float f){
  __bf16 h = (__bf16)f; unsigned short u; __builtin_memcpy(&u, &h, 2); return u;
}
__device__ __forceinline__ float gelu_f(float x){
  return 0.5f * x * (1.0f + erff(x * 0.70710678118654752f));
}
// fast sigmoid-gelu: max abs err ~0.01 vs exact
__device__ __forceinline__ float gelu_fast(float x){
  return x / (1.0f + __expf(-1.702f * x));
}
// overflow-safe fast tanh
__device__ __forceinline__ float tanh_fast(float x){
  float e = __expf(2.0f * x);
  return 1.0f - 2.0f / (e + 1.0f);
}

// ---------------- K_setup: fused tables + weight transposes + degree histogram ----------------
// blocks [0,35): tables; [35,1315): prep; [1315,2097): hist. All independent.
// Table k-loops carry an explicit unroll(16) so 16 global loads pipeline per chunk
// (serial-dependent loads were 64+ us of idle latency on 2 blocks).
__global__ __launch_bounds__(256) void k_setup(
    const float* __restrict__ task, const float* __restrict__ eemb,
    const float* __restrict__ msg_W, const float* __restrict__ msg_b,
    const float* __restrict__ att_W1, const float* __restrict__ att_b1,
    const float* __restrict__ ma_W1, const float* __restrict__ ma_b1,
    const float* __restrict__ ma_W2, const float* __restrict__ ma_b2,
    const float* __restrict__ ua_W1, const float* __restrict__ ua_b1,
    const float* __restrict__ ua_W2, const float* __restrict__ ua_b2,
    const float* __restrict__ up_W1, const float* __restrict__ up_W2,
    const int* __restrict__ eidx,
    float* __restrict__ tabs,
    unsigned short* __restrict__ WpreT, unsigned short* __restrict__ W1T,
    unsigned short* __restrict__ W2T, int* __restrict__ cnt)
{
  __shared__ float s_in[512];
  __shared__ float s_h[512];
  int bb = blockIdx.x, tid = threadIdx.x;
  if (bb >= 1315){
    int e = (bb - 1315)*256 + tid;
    if (e < NE) atomicAdd(&cnt[eidx[NE + e]], 1);
    return;
  }
  if (bb >= 35){
    int b = bb - 35;
    if (b < 768){
      int n = b;
      float v;
      if (n < 256)      v = msg_W[tid*256 + n];
      else if (n < 512) v = att_W1[tid*256 + (n - 256)];
      else              v = att_W1[(256 + tid)*256 + (n - 512)];
      WpreT[n*256 + tid] = f2bf(v);
    } else if (b < 1024){
      int n = b - 768;
      W1T[n*512 + tid]       = f2bf(up_W1[tid*256 + n]);
      W1T[n*512 + 256 + tid] = f2bf(up_W1[(256 + tid)*256 + n]);
    } else {
      int n = b - 1024;
      W2T[n*256 + tid] = f2bf(up_W2[tid*256 + n]);
    }
    return;
  }
  int b = bb;
  if (b < 2){
    const float* W1 = b ? ua_W1 : ma_W1;  const float* b1 = b ? ua_b1 : ma_b1;
    const float* W2 = b ? ua_W2 : ma_W2;  const float* b2 = b ? ua_b2 : ma_b2;
    s_in[tid] = task[tid];
    __syncthreads();
    #pragma unroll
    for (int jj = 0; jj < 2; ++jj){
      int j = tid + jj*256;
      float acc = b1[j];
      #pragma unroll 16
      for (int k = 0; k < 256; ++k) acc += s_in[k] * W1[k*512 + j];
      s_h[j] = gelu_f(acc);
    }
    __syncthreads();
    float o[2];
    #pragma unroll
    for (int jj = 0; jj < 2; ++jj){
      int j = tid + jj*256;
      float acc = b2[j];
      #pragma unroll 16
      for (int k = 0; k < 512; ++k) acc += s_h[k] * W2[k*512 + j];
      o[jj] = acc;
    }
    float* scale = tabs + (b ? TAB_UPD_SCALE : TAB_MSG_SCALE);
    float* beta  = tabs + (b ? TAB_UPD_BETA  : TAB_MSG_BETA);
    scale[tid] = 1.0f + 0.5f * tanhf(o[0]);
    beta[tid]  = o[1];
  } else if (b == 2){
    s_in[tid] = task[tid];
    __syncthreads();
    float acc = att_b1[tid];
    #pragma unroll 16
    for (int k = 0; k < 256; ++k) acc += s_in[k] * att_W1[(768 + k)*256 + tid];
    tabs[TAB_TASKC + tid] = acc;
  } else if (b < 19){
    int t = b - 3;
    s_in[tid] = eemb[t*256 + tid];
    __syncthreads();
    float acc = msg_b[tid];
    #pragma unroll 16
    for (int k = 0; k < 256; ++k) acc += s_in[k] * msg_W[k*256 + tid];
    tabs[TAB_EM + t*256 + tid] = acc;
  } else {
    int t = b - 19;
    s_in[tid] = eemb[t*256 + tid];
    __syncthreads();
    float acc = 0.f;
    #pragma unroll 16
    for (int k = 0; k < 256; ++k) acc += s_in[k] * att_W1[(512 + k)*256 + tid];
    tabs[TAB_EC + t*256 + tid] = acc;
  }
}

// ---------------- K1: G=[P1|M interleaved], P2b (proven) ----------------
__global__ __launch_bounds__(256) void k_gemm_pre(
    const float* __restrict__ X, const unsigned short* __restrict__ WpreT,
    const float* __restrict__ tabs,
    unsigned short* __restrict__ G, unsigned short* __restrict__ P2b)
{
  __shared__ __align__(16) unsigned short s_b[16*256]; // 8KB, swizzled elem ^= (n&7)<<3
  int tid = threadIdx.x, wv = tid >> 6, lane = tid & 63;
  int m0 = blockIdx.x*64 + wv*16;
  bool valid = (m0 < NN);
  int lo = lane & 15, hi = lane >> 4;
  bf16x8 a[8];
  if (valid){
    const float* xrow = X + (size_t)(m0 + lo)*256 + hi*8;
    #pragma unroll
    for (int kc = 0; kc < 8; ++kc){
      float4 f0 = *(const float4*)(xrow + kc*32);
      float4 f1 = *(const float4*)(xrow + kc*32 + 4);
      bf16x8 v;
      v[0]=(__bf16)f0.x; v[1]=(__bf16)f0.y; v[2]=(__bf16)f0.z; v[3]=(__bf16)f0.w;
      v[4]=(__bf16)f1.x; v[5]=(__bf16)f1.y; v[6]=(__bf16)f1.z; v[7]=(__bf16)f1.w;
      a[kc] = v;
    }
  }
  int sn = tid >> 4, sk0 = (tid & 15)*16;
  int sswz = (sn & 7) << 3;
  int rswz = (lo & 7) << 3;
  for (int nt = 0; nt < 48; ++nt){
    __syncthreads();
    {
      const unsigned short* gsrc = WpreT + (size_t)(nt*16 + sn)*256 + sk0;
      uint4 d0 = *(const uint4*)(gsrc);
      uint4 d1 = *(const uint4*)(gsrc + 8);
      *(uint4*)(s_b + sn*256 + (sk0 ^ sswz))       = d0;
      *(uint4*)(s_b + sn*256 + ((sk0 + 8) ^ sswz)) = d1;
    }
    __syncthreads();
    if (!valid) continue;
    f32x4 acc = {0.f, 0.f, 0.f, 0.f};
    #pragma unroll
    for (int kc = 0; kc < 8; ++kc){
      bf16x8 bfrag = *(const bf16x8*)(s_b + lo*256 + ((kc*32 + hi*8) ^ rswz));
      acc = __builtin_amdgcn_mfma_f32_16x16x32_bf16(a[kc], bfrag, acc, 0, 0, 0);
    }
    int n0 = nt*16;
    if (nt < 16){
      int j = n0 + lo;
      int elem = ((j >> 2) << 3) + 4 + (j & 3);
      unsigned short* grow = G + (size_t)(m0 + hi*4)*512 + elem;
      #pragma unroll
      for (int r = 0; r < 4; ++r) grow[(size_t)r*512] = f2bf(acc[r]);
    } else if (nt < 32){
      int j = n0 - 256 + lo;
      int elem = ((j >> 2) << 3) + (j & 3);
      unsigned short* grow = G + (size_t)(m0 + hi*4)*512 + elem;
      #pragma unroll
      for (int r = 0; r < 4; ++r) grow[(size_t)r*512] = f2bf(acc[r]);
    } else {
      int j = n0 - 512 + lo;
      float tcadd = tabs[TAB_TASKC + j];
      unsigned short* prow = P2b + (size_t)(m0 + hi*4)*256 + j;
      #pragma unroll
      for (int r = 0; r < 4; ++r) prow[(size_t)r*256] = f2bf(acc[r] + tcadd);
    }
  }
}

// ---------------- K2b: exclusive prefix sum (1 block, 20 elems/thread) ----------------
__global__ __launch_bounds__(1024) void k_scan(
    const int* __restrict__ cnt, int* __restrict__ ptrs, int* __restrict__ pwork)
{
  __shared__ int s[1024];
  int tid = threadIdx.x;
  int loc[20];
  int tot = 0;
  #pragma unroll
  for (int j = 0; j < 20; ++j){
    int i = tid*20 + j;
    loc[j] = tot;
    tot += (i < NN) ? cnt[i] : 0;
  }
  s[tid] = tot;
  __syncthreads();
  #pragma unroll
  for (int off = 1; off < 1024; off <<= 1){
    int t = (tid >= off) ? s[tid - off] : 0;
    __syncthreads();
    s[tid] += t;
    __syncthreads();
  }
  int base = s[tid] - tot;
  #pragma unroll
  for (int j = 0; j < 20; ++j){
    int i = tid*20 + j;
    if (i < NN){
      ptrs[i]  = base + loc[j];
      pwork[i] = base + loc[j];
    }
  }
  if (tid == 1023) ptrs[NN] = s[1023];
}

// ---------------- K2c: CSR build ----------------
__global__ __launch_bounds__(256) void k_csr_build(
    const int* __restrict__ eidx, const int* __restrict__ etype,
    int* __restrict__ pwork, unsigned int* __restrict__ srcet)
{
  int e = blockIdx.x*256 + threadIdx.x;
  if (e < NE){
    int dst = eidx[NE + e];
    int pos = atomicAdd(&pwork[dst], 1);
    srcet[pos] = (unsigned int)eidx[e] | ((unsigned int)etype[e] << 16);
  }
}

// ---------------- K3: fused attention + aggregate (proven round-6: 1 wave/node) ----------------
__global__ __launch_bounds__(256) void k_agg(
    const int* __restrict__ ptrs, const unsigned int* __restrict__ srcet,
    const unsigned short* __restrict__ G, const unsigned short* __restrict__ P2b,
    const float* __restrict__ tabs, const float* __restrict__ attW2,
    const float* __restrict__ attb2, const float* __restrict__ escale,
    unsigned short* __restrict__ updB)
{
  int node = blockIdx.x*4 + (threadIdx.x >> 6);
  if (node >= NN) return;
  int lane = threadIdx.x & 63, c0 = lane*4;
  ushort4 p2 = *(const ushort4*)(P2b + (size_t)node*256 + c0);
  float q0 = bf2f(p2.x), q1 = bf2f(p2.y), q2 = bf2f(p2.z), q3 = bf2f(p2.w);
  float4 w2 = *(const float4*)(attW2 + c0);
  float sc = escale[0], bb = attb2[0];
  float4 ms = *(const float4*)(tabs + TAB_MSG_SCALE + c0);
  float4 mb = *(const float4*)(tabs + TAB_MSG_BETA  + c0);
  float4 us = *(const float4*)(tabs + TAB_UPD_SCALE + c0);
  float4 ub = *(const float4*)(tabs + TAB_UPD_BETA  + c0);
  int start = ptrs[node], end = ptrs[node + 1];
  float ax = 0.f, ay = 0.f, az = 0.f, aw = 0.f, W = 0.f;
  unsigned int se0 = 0, se1 = 0;
  u16x8 g0 = {0,0,0,0,0,0,0,0};
  if (start < end){
    se0 = srcet[start];
    g0 = *(const u16x8*)(G + (size_t)(se0 & 0xFFFFu)*512 + lane*8);
    if (start + 1 < end) se1 = srcet[start + 1];
  }
  for (int i = start; i < end; ++i){
    u16x8 g1 = g0;
    unsigned int se2 = 0;
    if (i + 1 < end) g1 = *(const u16x8*)(G + (size_t)(se1 & 0xFFFFu)*512 + lane*8);
    if (i + 2 < end) se2 = srcet[i + 2];
    int et = (int)(se0 >> 16);
    float4 ec = *(const float4*)(tabs + TAB_EC + et*256 + c0);
    float part = gelu_fast(bf2f(g0[0]) + q0 + ec.x)*w2.x
               + gelu_fast(bf2f(g0[1]) + q1 + ec.y)*w2.y
               + gelu_fast(bf2f(g0[2]) + q2 + ec.z)*w2.z
               + gelu_fast(bf2f(g0[3]) + q3 + ec.w)*w2.w;
    #pragma unroll
    for (int off = 32; off; off >>= 1) part += __shfl_xor(part, off);
    float w = 1.0f + sc*tanh_fast(part + bb);
    float4 em = *(const float4*)(tabs + TAB_EM + et*256 + c0);
    ax += w*(bf2f(g0[4]) + em.x);
    ay += w*(bf2f(g0[5]) + em.y);
    az += w*(bf2f(g0[6]) + em.z);
    aw += w*(bf2f(g0[7]) + em.w);
    W += w;
    se0 = se1; se1 = se2; g0 = g1;
  }
  float d = fmaxf(W, 1.0f), rd = 1.0f / d;
  ushort4 st = { f2bf((ms.x*ax + mb.x*W)*rd*us.x + ub.x),
                 f2bf((ms.y*ay + mb.y*W)*rd*us.y + ub.y),
                 f2bf((ms.z*az + mb.z*W)*rd*us.z + ub.z),
                 f2bf((ms.w*aw + mb.w*W)*rd*us.w + ub.w) };
  *(ushort4*)(updB + (size_t)node*256 + c0) = st;
}

// ---------------- K4: 32-row dense MLP + residual + in-register LayerNorm (proven) ----------------
__device__ __forceinline__ bf16x8 ldA(const float* xrow, const unsigned short* urow, int ke){
  if (ke < 256){
    float4 f0 = *(const float4*)(xrow + ke);
    float4 f1 = *(const float4*)(xrow + ke + 4);
    bf16x8 v;
    v[0]=(__bf16)f0.x; v[1]=(__bf16)f0.y; v[2]=(__bf16)f0.z; v[3]=(__bf16)f0.w;
    v[4]=(__bf16)f1.x; v[5]=(__bf16)f1.y; v[6]=(__bf16)f1.z; v[7]=(__bf16)f1.w;
    return v;
  }
  return *(const bf16x8*)(urow + (ke - 256));
}

__global__ __launch_bounds__(256) void k_mlp(
    const float* __restrict__ X, const unsigned short* __restrict__ updB,
    const unsigned short* __restrict__ W1T, const unsigned short* __restrict__ W2T,
    const float* __restrict__ up_b1, const float* __restrict__ up_b2,
    const float* __restrict__ ln_g, const float* __restrict__ ln_b,
    float* __restrict__ out)
{
  __shared__ __align__(16) unsigned short s_H[32*256]; // bf16, ^=(row&7)<<3
  __shared__ float s_sum[4*32], s_sq[4*32];
  __shared__ float s_mu[32], s_rs[32];
  int m0 = blockIdx.x*32;
  int tid = threadIdx.x;
  int wv = tid >> 6, lane = tid & 63, lo = lane & 15, hi = lane >> 4;

  const float* x0 = X + (size_t)(m0 + lo)*256;
  const float* x1 = x0 + 16*256;
  const unsigned short* u0 = updB + (size_t)(m0 + lo)*256;
  const unsigned short* u1 = u0 + 16*256;

  f32x4 acc0[4], acc1[4];
  #pragma unroll
  for (int t = 0; t < 4; ++t){
    float b = up_b1[wv*64 + t*16 + lo];
    acc0[t] = (f32x4){b, b, b, b};
    acc1[t] = acc0[t];
  }
  #pragma unroll
  for (int kc = 0; kc < 16; ++kc){
    int ke = kc*32 + hi*8;
    bf16x8 a0 = ldA(x0, u0, ke);
    bf16x8 a1 = ldA(x1, u1, ke);
    #pragma unroll
    for (int t = 0; t < 4; ++t){
      int n = wv*64 + t*16 + lo;
      bf16x8 bf = *(const bf16x8*)(W1T + (size_t)n*512 + ke);
      acc0[t] = __builtin_amdgcn_mfma_f32_16x16x32_bf16(a0, bf, acc0[t], 0, 0, 0);
      acc1[t] = __builtin_amdgcn_mfma_f32_16x16x32_bf16(a1, bf, acc1[t], 0, 0, 0);
    }
  }
  #pragma unroll
  for (int t = 0; t < 4; ++t){
    #pragma unroll
    for (int r = 0; r < 4; ++r){
      int row0 = hi*4 + r, n = wv*64 + t*16 + lo;
      s_H[(row0 << 8) | (n ^ ((row0 & 7) << 3))] = f2bf(gelu_fast(acc0[t][r]));
      int row1 = row0 + 16;
      s_H[(row1 << 8) | (n ^ ((row1 & 7) << 3))] = f2bf(gelu_fast(acc1[t][r]));
    }
  }
  __syncthreads();

  f32x4 y0[4], y1[4];
  #pragma unroll
  for (int t = 0; t < 4; ++t){
    float b = up_b2[wv*64 + t*16 + lo];
    y0[t] = (f32x4){b, b, b, b};
    y1[t] = y0[t];
  }
  #pragma unroll
  for (int kc = 0; kc < 8; ++kc){
    int ke = kc*32 + hi*8;
    bf16x8 af0 = *(const bf16x8*)(s_H + ((lo << 8) | (ke ^ ((lo & 7) << 3))));
    int r1 = lo + 16;
    bf16x8 af1 = *(const bf16x8*)(s_H + ((r1 << 8) | (ke ^ ((r1 & 7) << 3))));
    #pragma unroll
    for (int t = 0; t < 4; ++t){
      int n = wv*64 + t*16 + lo;
      bf16x8 bf = *(const bf16x8*)(W2T + (size_t)n*256 + ke);
      y0[t] = __builtin_amdgcn_mfma_f32_16x16x32_bf16(af0, bf, y0[t], 0, 0, 0);
      y1[t] = __builtin_amdgcn_mfma_f32_16x16x32_bf16(af1, bf, y1[t], 0, 0, 0);
    }
  }

  #pragma unroll
  for (int t = 0; t < 4; ++t){
    #pragma unroll
    for (int r = 0; r < 4; ++r){
      int row0 = hi*4 + r, n = wv*64 + t*16 + lo;
      y0[t][r] += X[(size_t)(m0 + row0)*256 + n];
      y1[t][r] += X[(size_t)(m0 + row0 + 16)*256 + n];
    }
  }

  float ps[2][4], pq[2][4];
  #pragma unroll
  for (int r = 0; r < 4; ++r){
    float s0 = 0.f, q0 = 0.f, s1 = 0.f, q1 = 0.f;
    #pragma unroll
    for (int t = 0; t < 4; ++t){
      s0 += y0[t][r]; q0 += y0[t][r]*y0[t][r];
      s1 += y1[t][r]; q1 += y1[t][r]*y1[t][r];
    }
    #pragma unroll
    for (int off = 1; off < 16; off <<= 1){
      s0 += __shfl_xor(s0, off); q0 += __shfl_xor(q0, off);
      s1 += __shfl_xor(s1, off); q1 += __shfl_xor(q1, off);
    }
    ps[0][r] = s0; pq[0][r] = q0;
    ps[1][r] = s1; pq[1][r] = q1;
  }
  if (lo == 0){
    #pragma unroll
    for (int m = 0; m < 2; ++m){
      #pragma unroll
      for (int r = 0; r < 4; ++r){
        int row = m*16 + hi*4 + r;
        s_sum[wv*32 + row] = ps[m][r];
        s_sq [wv*32 + row] = pq[m][r];
      }
    }
  }
  __syncthreads();
  if (tid < 32){
    float sum = s_sum[tid] + s_sum[32 + tid] + s_sum[64 + tid] + s_sum[96 + tid];
    float sq  = s_sq[tid]  + s_sq[32 + tid]  + s_sq[64 + tid]  + s_sq[96 + tid];
    float mu = sum * (1.0f/256.0f);
    float var = sq * (1.0f/256.0f) - mu*mu;
    s_mu[tid] = mu;
    s_rs[tid] = rsqrtf(var + 1e-5f);
  }
  __syncthreads();

  #pragma unroll
  for (int t = 0; t < 4; ++t){
    int n = wv*64 + t*16 + lo;
    float lg = ln_g[n], lb = ln_b[n];
    #pragma unroll
    for (int r = 0; r < 4; ++r){
      int row0 = hi*4 + r, row1 = row0 + 16;
      out[(size_t)(m0 + row0)*256 + n] = (y0[t][r] - s_mu[row0]) * s_rs[row0] * lg + lb;
      out[(size_t)(m0 + row1)*256 + n] = (y1[t][r] - s_mu[row1]) * s_rs[row1] * lg + lb;
    }
  }
}

extern "C" void kernel_launch(void* const* d_in, const int* in_sizes, int n_in,
                              void* d_out, int out_size, void* d_ws, size_t ws_size,
                              hipStream_t stream)
{
  (void)in_sizes; (void)n_in; (void)out_size;
  if (ws_size < WS_NEED) return;
  const float* X      = (const float*)d_in[0];
  const int*   eidx   = (const int*)d_in[1];
  const int*   etype  = (const int*)d_in[2];
  const float* task   = (const float*)d_in[3];
  const float* eemb   = (const float*)d_in[4];
  const float* msg_W  = (const float*)d_in[5];
  const float* msg_b  = (const float*)d_in[6];
  const float* att_W1 = (const float*)d_in[7];
  const float* att_b1 = (const float*)d_in[8];
  const float* att_W2 = (const float*)d_in[9];
  const float* att_b2 = (const float*)d_in[10];
  const float* escale = (const float*)d_in[11];
  const float* ma_W1  = (const float*)d_in[12];
  const float* ma_b1  = (const float*)d_in[13];
  const float* ma_W2  = (const float*)d_in[14];
  const float* ma_b2  = (const float*)d_in[15];
  const float* up_W1  = (const float*)d_in[16];
  const float* up_b1  = (const float*)d_in[17];
  const float* up_W2  = (const float*)d_in[18];
  const float* up_b2  = (const float*)d_in[19];
  const float* ua_W1  = (const float*)d_in[20];
  const float* ua_b1  = (const float*)d_in[21];
  const float* ua_W2  = (const float*)d_in[22];
  const float* ua_b2  = (const float*)d_in[23];
  const float* ln_g   = (const float*)d_in[24];
  const float* ln_b   = (const float*)d_in[25];
  char* ws = (char*)d_ws;
  float* tabs = (float*)ws;
  unsigned short* WpreT = (unsigned short*)(ws + OFF_WPRET);
  unsigned short* W1T   = (unsigned short*)(ws + OFF_W1T);
  unsigned short* W2T   = (unsigned short*)(ws + OFF_W2T);
  int*          cnt   = (int*)(ws + OFF_CNT);
  int*          ptrs  = (int*)(ws + OFF_PTRS);
  int*          pwork = (int*)(ws + OFF_PWORK);
  unsigned int* srcet = (unsigned int*)(ws + OFF_SRCET);
  unsigned short* updB = (unsigned short*)(ws + OFF_UPDB);
  unsigned short* G    = (unsigned short*)(ws + OFF_G);
  unsigned short* P2b  = (unsigned short*)(ws + OFF_P2B);
  float* out = (float*)d_out;

  hipMemsetAsync(cnt, 0, (size_t)NN*4, stream);
  k_setup<<<2097, 256, 0, stream>>>(task, eemb, msg_W, msg_b, att_W1, att_b1,
                                    ma_W1, ma_b1, ma_W2, ma_b2,
                                    ua_W1, ua_b1, ua_W2, ua_b2,
                                    up_W1, up_W2, eidx,
                                    tabs, WpreT, W1T, W2T, cnt);
  k_gemm_pre<<<(NN + 63)/64, 256, 0, stream>>>(X, WpreT, tabs, G, P2b);
  k_scan<<<1, 1024, 0, stream>>>(cnt, ptrs, pwork);
  k_csr_build<<<(NE + 255)/256, 256, 0, stream>>>(eidx, etype, pwork, srcet);
  k_agg<<<(NN + 3)/4, 256, 0, stream>>>(ptrs, srcet, G, P2b, tabs,
                                        att_W2, att_b2, escale, updB);
  k_mlp<<<NN/32, 256, 0, stream>>>(X, updB, W1T, W2T, up_b1, up_b2,
                                   ln_g, ln_b, out);
}

// Round 11
// 246.537 us; speedup vs baseline: 1.1636x; 1.0341x over previous
//
#include <hip/hip_runtime.h>
#include <hip/hip_bf16.h>

#define NN 20000
#define NE 200000

typedef __bf16 bf16x8 __attribute__((ext_vector_type(8)));
typedef float f32x4 __attribute__((ext_vector_type(4)));
typedef unsigned short u16x8 __attribute__((ext_vector_type(8)));

// ---- workspace layout (bytes) ----
constexpr int TAB_MSG_SCALE = 0;      // f32 element offsets within tabs
constexpr int TAB_MSG_BETA  = 256;
constexpr int TAB_UPD_SCALE = 512;
constexpr int TAB_UPD_BETA  = 768;
constexpr int TAB_TASKC     = 1024;   // task @ att_W1[768:1024] + att_b1
constexpr int TAB_EM        = 1280;   // 16*256  e@msg_W + msg_b
constexpr int TAB_EC        = 1280 + 4096; // 16*256  e@att_W1[512:768]
constexpr size_t OFF_WPRET = 40960;    // u16[768*256] n-major
constexpr size_t OFF_W1T   = 434176;   // u16[256*512]
constexpr size_t OFF_W2T   = 696320;   // u16[256*256]
constexpr size_t OFF_CNT   = 827392;   // i32[NN]
constexpr size_t OFF_PTRS  = 907392;   // i32[NN+1]
constexpr size_t OFF_PWORK = 987648;   // i32[NN]
constexpr size_t OFF_SRCET = 1067648;  // u32[NE]  src | et<<16 (CSR order)
constexpr size_t OFF_UPDB  = 1867648;  // u16[NN*256]  aggregated+modulated upd half (bf16)
constexpr size_t OFF_G     = 12107648; // u16[NN*512]  interleaved [P1|M] per 4-dim group
constexpr size_t OFF_P2B   = 32587648; // u16[NN*256]  P2 + taskc (bf16)
constexpr size_t WS_NEED   = 42827648;

__device__ __forceinline__ float bf2f(unsigned short u){
  union { unsigned int i; float f; } v; v.i = ((unsigned int)u) << 16; return v.f;
}
__device__ __forceinline__ unsigned short f2bf(float f){
  __bf16 h = (__bf16)f; unsigned short u; __builtin_memcpy(&u, &h, 2); return u;
}
__device__ __forceinline__ float gelu_f(float x){
  return 0.5f * x * (1.0f + erff(x * 0.70710678118654752f));
}
// fast sigmoid-gelu: max abs err ~0.01 vs exact
__device__ __forceinline__ float gelu_fast(float x){
  return x / (1.0f + __expf(-1.702f * x));
}
// overflow-safe fast tanh
__device__ __forceinline__ float tanh_fast(float x){
  float e = __expf(2.0f * x);
  return 1.0f - 2.0f / (e + 1.0f);
}
__device__ __forceinline__ float sum16(const float* p){
  float a = ((p[0]+p[1])+(p[2]+p[3])) + ((p[4]+p[5])+(p[6]+p[7]));
  float b = ((p[8]+p[9])+(p[10]+p[11])) + ((p[12]+p[13])+(p[14]+p[15]));
  return a + b;
}

// ---------------- K_setup: fused tables + weight transposes + degree histogram ----------------
// blocks [0,35): tables; [35,1315): prep; [1315,2097): hist. All independent.
// Table dot-products use 16 partial accumulators + explicit 16-load batches:
// a single serial acc chain left only 1 load in flight (VGPR=20) -> 768 x ~230cyc
// = 73 us of pure latency on 2 blocks. 16 independent chains cut it ~16x.
__global__ __launch_bounds__(256) void k_setup(
    const float* __restrict__ task, const float* __restrict__ eemb,
    const float* __restrict__ msg_W, const float* __restrict__ msg_b,
    const float* __restrict__ att_W1, const float* __restrict__ att_b1,
    const float* __restrict__ ma_W1, const float* __restrict__ ma_b1,
    const float* __restrict__ ma_W2, const float* __restrict__ ma_b2,
    const float* __restrict__ ua_W1, const float* __restrict__ ua_b1,
    const float* __restrict__ ua_W2, const float* __restrict__ ua_b2,
    const float* __restrict__ up_W1, const float* __restrict__ up_W2,
    const int* __restrict__ eidx,
    float* __restrict__ tabs,
    unsigned short* __restrict__ WpreT, unsigned short* __restrict__ W1T,
    unsigned short* __restrict__ W2T, int* __restrict__ cnt)
{
  __shared__ float s_in[512];
  __shared__ float s_h[512];
  int bb = blockIdx.x, tid = threadIdx.x;
  if (bb >= 1315){
    int e = (bb - 1315)*256 + tid;
    if (e < NE) atomicAdd(&cnt[eidx[NE + e]], 1);
    return;
  }
  if (bb >= 35){
    int b = bb - 35;
    if (b < 768){
      int n = b;
      float v;
      if (n < 256)      v = msg_W[tid*256 + n];
      else if (n < 512) v = att_W1[tid*256 + (n - 256)];
      else              v = att_W1[(256 + tid)*256 + (n - 512)];
      WpreT[n*256 + tid] = f2bf(v);
    } else if (b < 1024){
      int n = b - 768;
      W1T[n*512 + tid]       = f2bf(up_W1[tid*256 + n]);
      W1T[n*512 + 256 + tid] = f2bf(up_W1[(256 + tid)*256 + n]);
    } else {
      int n = b - 1024;
      W2T[n*256 + tid] = f2bf(up_W2[tid*256 + n]);
    }
    return;
  }
  int b = bb;
  if (b < 2){
    const float* W1 = b ? ua_W1 : ma_W1;  const float* b1 = b ? ua_b1 : ma_b1;
    const float* W2 = b ? ua_W2 : ma_W2;  const float* b2 = b ? ua_b2 : ma_b2;
    s_in[tid] = task[tid];
    __syncthreads();
    #pragma unroll
    for (int jj = 0; jj < 2; ++jj){
      int j = tid + jj*256;
      float pacc[16];
      #pragma unroll
      for (int u = 0; u < 16; ++u) pacc[u] = 0.f;
      for (int k0 = 0; k0 < 256; k0 += 16){
        float wv[16];
        #pragma unroll
        for (int u = 0; u < 16; ++u) wv[u] = W1[(k0 + u)*512 + j];
        #pragma unroll
        for (int u = 0; u < 16; ++u) pacc[u] += s_in[k0 + u] * wv[u];
      }
      s_h[j] = gelu_f(b1[j] + sum16(pacc));
    }
    __syncthreads();
    float o[2];
    #pragma unroll
    for (int jj = 0; jj < 2; ++jj){
      int j = tid + jj*256;
      float pacc[16];
      #pragma unroll
      for (int u = 0; u < 16; ++u) pacc[u] = 0.f;
      for (int k0 = 0; k0 < 512; k0 += 16){
        float wv[16];
        #pragma unroll
        for (int u = 0; u < 16; ++u) wv[u] = W2[(k0 + u)*512 + j];
        #pragma unroll
        for (int u = 0; u < 16; ++u) pacc[u] += s_h[k0 + u] * wv[u];
      }
      o[jj] = b2[j] + sum16(pacc);
    }
    float* scale = tabs + (b ? TAB_UPD_SCALE : TAB_MSG_SCALE);
    float* beta  = tabs + (b ? TAB_UPD_BETA  : TAB_MSG_BETA);
    scale[tid] = 1.0f + 0.5f * tanhf(o[0]);
    beta[tid]  = o[1];
  } else if (b == 2){
    s_in[tid] = task[tid];
    __syncthreads();
    float pacc[16];
    #pragma unroll
    for (int u = 0; u < 16; ++u) pacc[u] = 0.f;
    for (int k0 = 0; k0 < 256; k0 += 16){
      float wv[16];
      #pragma unroll
      for (int u = 0; u < 16; ++u) wv[u] = att_W1[(768 + k0 + u)*256 + tid];
      #pragma unroll
      for (int u = 0; u < 16; ++u) pacc[u] += s_in[k0 + u] * wv[u];
    }
    tabs[TAB_TASKC + tid] = att_b1[tid] + sum16(pacc);
  } else if (b < 19){
    int t = b - 3;
    s_in[tid] = eemb[t*256 + tid];
    __syncthreads();
    float pacc[16];
    #pragma unroll
    for (int u = 0; u < 16; ++u) pacc[u] = 0.f;
    for (int k0 = 0; k0 < 256; k0 += 16){
      float wv[16];
      #pragma unroll
      for (int u = 0; u < 16; ++u) wv[u] = msg_W[(k0 + u)*256 + tid];
      #pragma unroll
      for (int u = 0; u < 16; ++u) pacc[u] += s_in[k0 + u] * wv[u];
    }
    tabs[TAB_EM + t*256 + tid] = msg_b[tid] + sum16(pacc);
  } else {
    int t = b - 19;
    s_in[tid] = eemb[t*256 + tid];
    __syncthreads();
    float pacc[16];
    #pragma unroll
    for (int u = 0; u < 16; ++u) pacc[u] = 0.f;
    for (int k0 = 0; k0 < 256; k0 += 16){
      float wv[16];
      #pragma unroll
      for (int u = 0; u < 16; ++u) wv[u] = att_W1[(512 + k0 + u)*256 + tid];
      #pragma unroll
      for (int u = 0; u < 16; ++u) pacc[u] += s_in[k0 + u] * wv[u];
    }
    tabs[TAB_EC + t*256 + tid] = sum16(pacc);
  }
}

// ---------------- K1: G=[P1|M interleaved], P2b (proven) ----------------
__global__ __launch_bounds__(256) void k_gemm_pre(
    const float* __restrict__ X, const unsigned short* __restrict__ WpreT,
    const float* __restrict__ tabs,
    unsigned short* __restrict__ G, unsigned short* __restrict__ P2b)
{
  __shared__ __align__(16) unsigned short s_b[16*256]; // 8KB, swizzled elem ^= (n&7)<<3
  int tid = threadIdx.x, wv = tid >> 6, lane = tid & 63;
  int m0 = blockIdx.x*64 + wv*16;
  bool valid = (m0 < NN);
  int lo = lane & 15, hi = lane >> 4;
  bf16x8 a[8];
  if (valid){
    const float* xrow = X + (size_t)(m0 + lo)*256 + hi*8;
    #pragma unroll
    for (int kc = 0; kc < 8; ++kc){
      float4 f0 = *(const float4*)(xrow + kc*32);
      float4 f1 = *(const float4*)(xrow + kc*32 + 4);
      bf16x8 v;
      v[0]=(__bf16)f0.x; v[1]=(__bf16)f0.y; v[2]=(__bf16)f0.z; v[3]=(__bf16)f0.w;
      v[4]=(__bf16)f1.x; v[5]=(__bf16)f1.y; v[6]=(__bf16)f1.z; v[7]=(__bf16)f1.w;
      a[kc] = v;
    }
  }
  int sn = tid >> 4, sk0 = (tid & 15)*16;
  int sswz = (sn & 7) << 3;
  int rswz = (lo & 7) << 3;
  for (int nt = 0; nt < 48; ++nt){
    __syncthreads();
    {
      const unsigned short* gsrc = WpreT + (size_t)(nt*16 + sn)*256 + sk0;
      uint4 d0 = *(const uint4*)(gsrc);
      uint4 d1 = *(const uint4*)(gsrc + 8);
      *(uint4*)(s_b + sn*256 + (sk0 ^ sswz))       = d0;
      *(uint4*)(s_b + sn*256 + ((sk0 + 8) ^ sswz)) = d1;
    }
    __syncthreads();
    if (!valid) continue;
    f32x4 acc = {0.f, 0.f, 0.f, 0.f};
    #pragma unroll
    for (int kc = 0; kc < 8; ++kc){
      bf16x8 bfrag = *(const bf16x8*)(s_b + lo*256 + ((kc*32 + hi*8) ^ rswz));
      acc = __builtin_amdgcn_mfma_f32_16x16x32_bf16(a[kc], bfrag, acc, 0, 0, 0);
    }
    int n0 = nt*16;
    if (nt < 16){
      int j = n0 + lo;
      int elem = ((j >> 2) << 3) + 4 + (j & 3);
      unsigned short* grow = G + (size_t)(m0 + hi*4)*512 + elem;
      #pragma unroll
      for (int r = 0; r < 4; ++r) grow[(size_t)r*512] = f2bf(acc[r]);
    } else if (nt < 32){
      int j = n0 - 256 + lo;
      int elem = ((j >> 2) << 3) + (j & 3);
      unsigned short* grow = G + (size_t)(m0 + hi*4)*512 + elem;
      #pragma unroll
      for (int r = 0; r < 4; ++r) grow[(size_t)r*512] = f2bf(acc[r]);
    } else {
      int j = n0 - 512 + lo;
      float tcadd = tabs[TAB_TASKC + j];
      unsigned short* prow = P2b + (size_t)(m0 + hi*4)*256 + j;
      #pragma unroll
      for (int r = 0; r < 4; ++r) prow[(size_t)r*256] = f2bf(acc[r] + tcadd);
    }
  }
}

// ---------------- K2b: exclusive prefix sum (1 block, 20 elems/thread) ----------------
__global__ __launch_bounds__(1024) void k_scan(
    const int* __restrict__ cnt, int* __restrict__ ptrs, int* __restrict__ pwork)
{
  __shared__ int s[1024];
  int tid = threadIdx.x;
  int loc[20];
  int tot = 0;
  #pragma unroll
  for (int j = 0; j < 20; ++j){
    int i = tid*20 + j;
    loc[j] = tot;
    tot += (i < NN) ? cnt[i] : 0;
  }
  s[tid] = tot;
  __syncthreads();
  #pragma unroll
  for (int off = 1; off < 1024; off <<= 1){
    int t = (tid >= off) ? s[tid - off] : 0;
    __syncthreads();
    s[tid] += t;
    __syncthreads();
  }
  int base = s[tid] - tot;
  #pragma unroll
  for (int j = 0; j < 20; ++j){
    int i = tid*20 + j;
    if (i < NN){
      ptrs[i]  = base + loc[j];
      pwork[i] = base + loc[j];
    }
  }
  if (tid == 1023) ptrs[NN] = s[1023];
}

// ---------------- K2c: CSR build ----------------
__global__ __launch_bounds__(256) void k_csr_build(
    const int* __restrict__ eidx, const int* __restrict__ etype,
    int* __restrict__ pwork, unsigned int* __restrict__ srcet)
{
  int e = blockIdx.x*256 + threadIdx.x;
  if (e < NE){
    int dst = eidx[NE + e];
    int pos = atomicAdd(&pwork[dst], 1);
    srcet[pos] = (unsigned int)eidx[e] | ((unsigned int)etype[e] << 16);
  }
}

// ---------------- K3: fused attention + aggregate (proven round-6: 1 wave/node) ----------------
__global__ __launch_bounds__(256) void k_agg(
    const int* __restrict__ ptrs, const unsigned int* __restrict__ srcet,
    const unsigned short* __restrict__ G, const unsigned short* __restrict__ P2b,
    const float* __restrict__ tabs, const float* __restrict__ attW2,
    const float* __restrict__ attb2, const float* __restrict__ escale,
    unsigned short* __restrict__ updB)
{
  int node = blockIdx.x*4 + (threadIdx.x >> 6);
  if (node >= NN) return;
  int lane = threadIdx.x & 63, c0 = lane*4;
  ushort4 p2 = *(const ushort4*)(P2b + (size_t)node*256 + c0);
  float q0 = bf2f(p2.x), q1 = bf2f(p2.y), q2 = bf2f(p2.z), q3 = bf2f(p2.w);
  float4 w2 = *(const float4*)(attW2 + c0);
  float sc = escale[0], bb = attb2[0];
  float4 ms = *(const float4*)(tabs + TAB_MSG_SCALE + c0);
  float4 mb = *(const float4*)(tabs + TAB_MSG_BETA  + c0);
  float4 us = *(const float4*)(tabs + TAB_UPD_SCALE + c0);
  float4 ub = *(const float4*)(tabs + TAB_UPD_BETA  + c0);
  int start = ptrs[node], end = ptrs[node + 1];
  float ax = 0.f, ay = 0.f, az = 0.f, aw = 0.f, W = 0.f;
  unsigned int se0 = 0, se1 = 0;
  u16x8 g0 = {0,0,0,0,0,0,0,0};
  if (start < end){
    se0 = srcet[start];
    g0 = *(const u16x8*)(G + (size_t)(se0 & 0xFFFFu)*512 + lane*8);
    if (start + 1 < end) se1 = srcet[start + 1];
  }
  for (int i = start; i < end; ++i){
    u16x8 g1 = g0;
    unsigned int se2 = 0;
    if (i + 1 < end) g1 = *(const u16x8*)(G + (size_t)(se1 & 0xFFFFu)*512 + lane*8);
    if (i + 2 < end) se2 = srcet[i + 2];
    int et = (int)(se0 >> 16);
    float4 ec = *(const float4*)(tabs + TAB_EC + et*256 + c0);
    float part = gelu_fast(bf2f(g0[0]) + q0 + ec.x)*w2.x
               + gelu_fast(bf2f(g0[1]) + q1 + ec.y)*w2.y
               + gelu_fast(bf2f(g0[2]) + q2 + ec.z)*w2.z
               + gelu_fast(bf2f(g0[3]) + q3 + ec.w)*w2.w;
    #pragma unroll
    for (int off = 32; off; off >>= 1) part += __shfl_xor(part, off);
    float w = 1.0f + sc*tanh_fast(part + bb);
    float4 em = *(const float4*)(tabs + TAB_EM + et*256 + c0);
    ax += w*(bf2f(g0[4]) + em.x);
    ay += w*(bf2f(g0[5]) + em.y);
    az += w*(bf2f(g0[6]) + em.z);
    aw += w*(bf2f(g0[7]) + em.w);
    W += w;
    se0 = se1; se1 = se2; g0 = g1;
  }
  float d = fmaxf(W, 1.0f), rd = 1.0f / d;
  ushort4 st = { f2bf((ms.x*ax + mb.x*W)*rd*us.x + ub.x),
                 f2bf((ms.y*ay + mb.y*W)*rd*us.y + ub.y),
                 f2bf((ms.z*az + mb.z*W)*rd*us.z + ub.z),
                 f2bf((ms.w*aw + mb.w*W)*rd*us.w + ub.w) };
  *(ushort4*)(updB + (size_t)node*256 + c0) = st;
}

// ---------------- K4: 32-row dense MLP + residual + in-register LayerNorm (proven) ----------------
__device__ __forceinline__ bf16x8 ldA(const float* xrow, const unsigned short* urow, int ke){
  if (ke < 256){
    float4 f0 = *(const float4*)(xrow + ke);
    float4 f1 = *(const float4*)(xrow + ke + 4);
    bf16x8 v;
    v[0]=(__bf16)f0.x; v[1]=(__bf16)f0.y; v[2]=(__bf16)f0.z; v[3]=(__bf16)f0.w;
    v[4]=(__bf16)f1.x; v[5]=(__bf16)f1.y; v[6]=(__bf16)f1.z; v[7]=(__bf16)f1.w;
    return v;
  }
  return *(const bf16x8*)(urow + (ke - 256));
}

__global__ __launch_bounds__(256) void k_mlp(
    const float* __restrict__ X, const unsigned short* __restrict__ updB,
    const unsigned short* __restrict__ W1T, const unsigned short* __restrict__ W2T,
    const float* __restrict__ up_b1, const float* __restrict__ up_b2,
    const float* __restrict__ ln_g, const float* __restrict__ ln_b,
    float* __restrict__ out)
{
  __shared__ __align__(16) unsigned short s_H[32*256]; // bf16, ^=(row&7)<<3
  __shared__ float s_sum[4*32], s_sq[4*32];
  __shared__ float s_mu[32], s_rs[32];
  int m0 = blockIdx.x*32;
  int tid = threadIdx.x;
  int wv = tid >> 6, lane = tid & 63, lo = lane & 15, hi = lane >> 4;

  const float* x0 = X + (size_t)(m0 + lo)*256;
  const float* x1 = x0 + 16*256;
  const unsigned short* u0 = updB + (size_t)(m0 + lo)*256;
  const unsigned short* u1 = u0 + 16*256;

  f32x4 acc0[4], acc1[4];
  #pragma unroll
  for (int t = 0; t < 4; ++t){
    float b = up_b1[wv*64 + t*16 + lo];
    acc0[t] = (f32x4){b, b, b, b};
    acc1[t] = acc0[t];
  }
  #pragma unroll
  for (int kc = 0; kc < 16; ++kc){
    int ke = kc*32 + hi*8;
    bf16x8 a0 = ldA(x0, u0, ke);
    bf16x8 a1 = ldA(x1, u1, ke);
    #pragma unroll
    for (int t = 0; t < 4; ++t){
      int n = wv*64 + t*16 + lo;
      bf16x8 bf = *(const bf16x8*)(W1T + (size_t)n*512 + ke);
      acc0[t] = __builtin_amdgcn_mfma_f32_16x16x32_bf16(a0, bf, acc0[t], 0, 0, 0);
      acc1[t] = __builtin_amdgcn_mfma_f32_16x16x32_bf16(a1, bf, acc1[t], 0, 0, 0);
    }
  }
  #pragma unroll
  for (int t = 0; t < 4; ++t){
    #pragma unroll
    for (int r = 0; r < 4; ++r){
      int row0 = hi*4 + r, n = wv*64 + t*16 + lo;
      s_H[(row0 << 8) | (n ^ ((row0 & 7) << 3))] = f2bf(gelu_fast(acc0[t][r]));
      int row1 = row0 + 16;
      s_H[(row1 << 8) | (n ^ ((row1 & 7) << 3))] = f2bf(gelu_fast(acc1[t][r]));
    }
  }
  __syncthreads();

  f32x4 y0[4], y1[4];
  #pragma unroll
  for (int t = 0; t < 4; ++t){
    float b = up_b2[wv*64 + t*16 + lo];
    y0[t] = (f32x4){b, b, b, b};
    y1[t] = y0[t];
  }
  #pragma unroll
  for (int kc = 0; kc < 8; ++kc){
    int ke = kc*32 + hi*8;
    bf16x8 af0 = *(const bf16x8*)(s_H + ((lo << 8) | (ke ^ ((lo & 7) << 3))));
    int r1 = lo + 16;
    bf16x8 af1 = *(const bf16x8*)(s_H + ((r1 << 8) | (ke ^ ((r1 & 7) << 3))));
    #pragma unroll
    for (int t = 0; t < 4; ++t){
      int n = wv*64 + t*16 + lo;
      bf16x8 bf = *(const bf16x8*)(W2T + (size_t)n*256 + ke);
      y0[t] = __builtin_amdgcn_mfma_f32_16x16x32_bf16(af0, bf, y0[t], 0, 0, 0);
      y1[t] = __builtin_amdgcn_mfma_f32_16x16x32_bf16(af1, bf, y1[t], 0, 0, 0);
    }
  }

  #pragma unroll
  for (int t = 0; t < 4; ++t){
    #pragma unroll
    for (int r = 0; r < 4; ++r){
      int row0 = hi*4 + r, n = wv*64 + t*16 + lo;
      y0[t][r] += X[(size_t)(m0 + row0)*256 + n];
      y1[t][r] += X[(size_t)(m0 + row0 + 16)*256 + n];
    }
  }

  float ps[2][4], pq[2][4];
  #pragma unroll
  for (int r = 0; r < 4; ++r){
    float s0 = 0.f, q0 = 0.f, s1 = 0.f, q1 = 0.f;
    #pragma unroll
    for (int t = 0; t < 4; ++t){
      s0 += y0[t][r]; q0 += y0[t][r]*y0[t][r];
      s1 += y1[t][r]; q1 += y1[t][r]*y1[t][r];
    }
    #pragma unroll
    for (int off = 1; off < 16; off <<= 1){
      s0 += __shfl_xor(s0, off); q0 += __shfl_xor(q0, off);
      s1 += __shfl_xor(s1, off); q1 += __shfl_xor(q1, off);
    }
    ps[0][r] = s0; pq[0][r] = q0;
    ps[1][r] = s1; pq[1][r] = q1;
  }
  if (lo == 0){
    #pragma unroll
    for (int m = 0; m < 2; ++m){
      #pragma unroll
      for (int r = 0; r < 4; ++r){
        int row = m*16 + hi*4 + r;
        s_sum[wv*32 + row] = ps[m][r];
        s_sq [wv*32 + row] = pq[m][r];
      }
    }
  }
  __syncthreads();
  if (tid < 32){
    float sum = s_sum[tid] + s_sum[32 + tid] + s_sum[64 + tid] + s_sum[96 + tid];
    float sq  = s_sq[tid]  + s_sq[32 + tid]  + s_sq[64 + tid]  + s_sq[96 + tid];
    float mu = sum * (1.0f/256.0f);
    float var = sq * (1.0f/256.0f) - mu*mu;
    s_mu[tid] = mu;
    s_rs[tid] = rsqrtf(var + 1e-5f);
  }
  __syncthreads();

  #pragma unroll
  for (int t = 0; t < 4; ++t){
    int n = wv*64 + t*16 + lo;
    float lg = ln_g[n], lb = ln_b[n];
    #pragma unroll
    for (int r = 0; r < 4; ++r){
      int row0 = hi*4 + r, row1 = row0 + 16;
      out[(size_t)(m0 + row0)*256 + n] = (y0[t][r] - s_mu[row0]) * s_rs[row0] * lg + lb;
      out[(size_t)(m0 + row1)*256 + n] = (y1[t][r] - s_mu[row1]) * s_rs[row1] * lg + lb;
    }
  }
}

extern "C" void kernel_launch(void* const* d_in, const int* in_sizes, int n_in,
                              void* d_out, int out_size, void* d_ws, size_t ws_size,
                              hipStream_t stream)
{
  (void)in_sizes; (void)n_in; (void)out_size;
  if (ws_size < WS_NEED) return;
  const float* X      = (const float*)d_in[0];
  const int*   eidx   = (const int*)d_in[1];
  const int*   etype  = (const int*)d_in[2];
  const float* task   = (const float*)d_in[3];
  const float* eemb   = (const float*)d_in[4];
  const float* msg_W  = (const float*)d_in[5];
  const float* msg_b  = (const float*)d_in[6];
  const float* att_W1 = (const float*)d_in[7];
  const float* att_b1 = (const float*)d_in[8];
  const float* att_W2 = (const float*)d_in[9];
  const float* att_b2 = (const float*)d_in[10];
  const float* escale = (const float*)d_in[11];
  const float* ma_W1  = (const float*)d_in[12];
  const float* ma_b1  = (const float*)d_in[13];
  const float* ma_W2  = (const float*)d_in[14];
  const float* ma_b2  = (const float*)d_in[15];
  const float* up_W1  = (const float*)d_in[16];
  const float* up_b1  = (const float*)d_in[17];
  const float* up_W2  = (const float*)d_in[18];
  const float* up_b2  = (const float*)d_in[19];
  const float* ua_W1  = (const float*)d_in[20];
  const float* ua_b1  = (const float*)d_in[21];
  const float* ua_W2  = (const float*)d_in[22];
  const float* ua_b2  = (const float*)d_in[23];
  const float* ln_g   = (const float*)d_in[24];
  const float* ln_b   = (const float*)d_in[25];
  char* ws = (char*)d_ws;
  float* tabs = (float*)ws;
  unsigned short* WpreT = (unsigned short*)(ws + OFF_WPRET);
  unsigned short* W1T   = (unsigned short*)(ws + OFF_W1T);
  unsigned short* W2T   = (unsigned short*)(ws + OFF_W2T);
  int*          cnt   = (int*)(ws + OFF_CNT);
  int*          ptrs  = (int*)(ws + OFF_PTRS);
  int*          pwork = (int*)(ws + OFF_PWORK);
  unsigned int* srcet = (unsigned int*)(ws + OFF_SRCET);
  unsigned short* updB = (unsigned short*)(ws + OFF_UPDB);
  unsigned short* G    = (unsigned short*)(ws + OFF_G);
  unsigned short* P2b  = (unsigned short*)(ws + OFF_P2B);
  float* out = (float*)d_out;

  hipMemsetAsync(cnt, 0, (size_t)NN*4, stream);
  k_setup<<<2097, 256, 0, stream>>>(task, eemb, msg_W, msg_b, att_W1, att_b1,
                                    ma_W1, ma_b1, ma_W2, ma_b2,
                                    ua_W1, ua_b1, ua_W2, ua_b2,
                                    up_W1, up_W2, eidx,
                                    tabs, WpreT, W1T, W2T, cnt);
  k_gemm_pre<<<(NN + 63)/64, 256, 0, stream>>>(X, WpreT, tabs, G, P2b);
  k_scan<<<1, 1024, 0, stream>>>(cnt, ptrs, pwork);
  k_csr_build<<<(NE + 255)/256, 256, 0, stream>>>(eidx, etype, pwork, srcet);
  k_agg<<<(NN + 3)/4, 256, 0, stream>>>(ptrs, srcet, G, P2b, tabs,
                                        att_W2, att_b2, escale, updB);
  k_mlp<<<NN/32, 256, 0, stream>>>(X, updB, W1T, W2T, up_b1, up_b2,
                                   ln_g, ln_b, out);
}

// Round 12
// 241.952 us; speedup vs baseline: 1.1856x; 1.0189x over previous
//
#include <hip/hip_runtime.h>
#include <hip/hip_bf16.h>

#define NN 20000
#define NE 200000

typedef __bf16 bf16x8 __attribute__((ext_vector_type(8)));
typedef float f32x4 __attribute__((ext_vector_type(4)));
typedef unsigned short u16x8 __attribute__((ext_vector_type(8)));

// ---- workspace layout (bytes) ----
constexpr int TAB_MSG_SCALE = 0;      // f32 element offsets within tabs
constexpr int TAB_MSG_BETA  = 256;
constexpr int TAB_UPD_SCALE = 512;
constexpr int TAB_UPD_BETA  = 768;
constexpr int TAB_TASKC     = 1024;   // task @ att_W1[768:1024] + att_b1
constexpr int TAB_ECM       = 1280;   // 16*512: per 4-dim group g: [ec[4g..] | em[4g..]]
constexpr size_t OFF_WPRET = 40960;    // u16[768*256] n-major
constexpr size_t OFF_W1T   = 434176;   // u16[256*512]
constexpr size_t OFF_W2T   = 696320;   // u16[256*256]
constexpr size_t OFF_CNT   = 827392;   // i32[NN]
constexpr size_t OFF_PTRS  = 907392;   // i32[NN+1]
constexpr size_t OFF_PWORK = 987648;   // i32[NN]
constexpr size_t OFF_SRCET = 1067648;  // u32[NE]  src | et<<16 (CSR order)
constexpr size_t OFF_UPDB  = 1867648;  // u16[NN*256]  aggregated+modulated upd half (bf16)
constexpr size_t OFF_G     = 12107648; // u16[NN*512]  interleaved [P1|M] per 4-dim group
constexpr size_t OFF_P2B   = 32587648; // u16[NN*256]  P2 + taskc (bf16)
constexpr size_t WS_NEED   = 42827648;

constexpr int GEMM_BLOCKS = (NN + 63)/64;   // 313 compute blocks; block 313 = scan

__device__ __forceinline__ float bf2f(unsigned short u){
  union { unsigned int i; float f; } v; v.i = ((unsigned int)u) << 16; return v.f;
}
__device__ __forceinline__ unsigned short f2bf(float f){
  __bf16 h = (__bf16)f; unsigned short u; __builtin_memcpy(&u, &h, 2); return u;
}
__device__ __forceinline__ float gelu_f(float x){
  return 0.5f * x * (1.0f + erff(x * 0.70710678118654752f));
}
// fast sigmoid-gelu: max abs err ~0.01 vs exact
__device__ __forceinline__ float gelu_fast(float x){
  return x / (1.0f + __expf(-1.702f * x));
}
// overflow-safe fast tanh
__device__ __forceinline__ float tanh_fast(float x){
  float e = __expf(2.0f * x);
  return 1.0f - 2.0f / (e + 1.0f);
}
__device__ __forceinline__ float sum16(const float* p){
  float a = ((p[0]+p[1])+(p[2]+p[3])) + ((p[4]+p[5])+(p[6]+p[7]));
  float b = ((p[8]+p[9])+(p[10]+p[11])) + ((p[12]+p[13])+(p[14]+p[15]));
  return a + b;
}

// ---------------- K_setup: fused tables + weight transposes + degree histogram ----------------
// blocks [0,35): tables; [35,1315): prep; [1315,2097): hist. All independent.
// Table dot-products use 16 partial accumulators + explicit 16-load batches.
__global__ __launch_bounds__(256) void k_setup(
    const float* __restrict__ task, const float* __restrict__ eemb,
    const float* __restrict__ msg_W, const float* __restrict__ msg_b,
    const float* __restrict__ att_W1, const float* __restrict__ att_b1,
    const float* __restrict__ ma_W1, const float* __restrict__ ma_b1,
    const float* __restrict__ ma_W2, const float* __restrict__ ma_b2,
    const float* __restrict__ ua_W1, const float* __restrict__ ua_b1,
    const float* __restrict__ ua_W2, const float* __restrict__ ua_b2,
    const float* __restrict__ up_W1, const float* __restrict__ up_W2,
    const int* __restrict__ eidx,
    float* __restrict__ tabs,
    unsigned short* __restrict__ WpreT, unsigned short* __restrict__ W1T,
    unsigned short* __restrict__ W2T, int* __restrict__ cnt)
{
  __shared__ float s_in[512];
  __shared__ float s_h[512];
  int bb = blockIdx.x, tid = threadIdx.x;
  if (bb >= 1315){
    int e = (bb - 1315)*256 + tid;
    if (e < NE) atomicAdd(&cnt[eidx[NE + e]], 1);
    return;
  }
  if (bb >= 35){
    int b = bb - 35;
    if (b < 768){
      int n = b;
      float v;
      if (n < 256)      v = msg_W[tid*256 + n];
      else if (n < 512) v = att_W1[tid*256 + (n - 256)];
      else              v = att_W1[(256 + tid)*256 + (n - 512)];
      WpreT[n*256 + tid] = f2bf(v);
    } else if (b < 1024){
      int n = b - 768;
      W1T[n*512 + tid]       = f2bf(up_W1[tid*256 + n]);
      W1T[n*512 + 256 + tid] = f2bf(up_W1[(256 + tid)*256 + n]);
    } else {
      int n = b - 1024;
      W2T[n*256 + tid] = f2bf(up_W2[tid*256 + n]);
    }
    return;
  }
  int b = bb;
  if (b < 2){
    const float* W1 = b ? ua_W1 : ma_W1;  const float* b1 = b ? ua_b1 : ma_b1;
    const float* W2 = b ? ua_W2 : ma_W2;  const float* b2 = b ? ua_b2 : ma_b2;
    s_in[tid] = task[tid];
    __syncthreads();
    #pragma unroll
    for (int jj = 0; jj < 2; ++jj){
      int j = tid + jj*256;
      float pacc[16];
      #pragma unroll
      for (int u = 0; u < 16; ++u) pacc[u] = 0.f;
      for (int k0 = 0; k0 < 256; k0 += 16){
        float wv[16];
        #pragma unroll
        for (int u = 0; u < 16; ++u) wv[u] = W1[(k0 + u)*512 + j];
        #pragma unroll
        for (int u = 0; u < 16; ++u) pacc[u] += s_in[k0 + u] * wv[u];
      }
      s_h[j] = gelu_f(b1[j] + sum16(pacc));
    }
    __syncthreads();
    float o[2];
    #pragma unroll
    for (int jj = 0; jj < 2; ++jj){
      int j = tid + jj*256;
      float pacc[16];
      #pragma unroll
      for (int u = 0; u < 16; ++u) pacc[u] = 0.f;
      for (int k0 = 0; k0 < 512; k0 += 16){
        float wv[16];
        #pragma unroll
        for (int u = 0; u < 16; ++u) wv[u] = W2[(k0 + u)*512 + j];
        #pragma unroll
        for (int u = 0; u < 16; ++u) pacc[u] += s_h[k0 + u] * wv[u];
      }
      o[jj] = b2[j] + sum16(pacc);
    }
    float* scale = tabs + (b ? TAB_UPD_SCALE : TAB_MSG_SCALE);
    float* beta  = tabs + (b ? TAB_UPD_BETA  : TAB_MSG_BETA);
    scale[tid] = 1.0f + 0.5f * tanhf(o[0]);
    beta[tid]  = o[1];
  } else if (b == 2){
    s_in[tid] = task[tid];
    __syncthreads();
    float pacc[16];
    #pragma unroll
    for (int u = 0; u < 16; ++u) pacc[u] = 0.f;
    for (int k0 = 0; k0 < 256; k0 += 16){
      float wv[16];
      #pragma unroll
      for (int u = 0; u < 16; ++u) wv[u] = att_W1[(768 + k0 + u)*256 + tid];
      #pragma unroll
      for (int u = 0; u < 16; ++u) pacc[u] += s_in[k0 + u] * wv[u];
    }
    tabs[TAB_TASKC + tid] = att_b1[tid] + sum16(pacc);
  } else if (b < 19){
    // EM (message table): ECM group-interleaved, +4 half
    int t = b - 3;
    s_in[tid] = eemb[t*256 + tid];
    __syncthreads();
    float pacc[16];
    #pragma unroll
    for (int u = 0; u < 16; ++u) pacc[u] = 0.f;
    for (int k0 = 0; k0 < 256; k0 += 16){
      float wv[16];
      #pragma unroll
      for (int u = 0; u < 16; ++u) wv[u] = msg_W[(k0 + u)*256 + tid];
      #pragma unroll
      for (int u = 0; u < 16; ++u) pacc[u] += s_in[k0 + u] * wv[u];
    }
    tabs[TAB_ECM + t*512 + ((tid >> 2) << 3) + 4 + (tid & 3)] = msg_b[tid] + sum16(pacc);
  } else {
    // EC (attention table): ECM group-interleaved, base half
    int t = b - 19;
    s_in[tid] = eemb[t*256 + tid];
    __syncthreads();
    float pacc[16];
    #pragma unroll
    for (int u = 0; u < 16; ++u) pacc[u] = 0.f;
    for (int k0 = 0; k0 < 256; k0 += 16){
      float wv[16];
      #pragma unroll
      for (int u = 0; u < 16; ++u) wv[u] = att_W1[(512 + k0 + u)*256 + tid];
      #pragma unroll
      for (int u = 0; u < 16; ++u) pacc[u] += s_in[k0 + u] * wv[u];
    }
    tabs[TAB_ECM + t*512 + ((tid >> 2) << 3) + (tid & 3)] = sum16(pacc);
  }
}

// ---------------- K1: G=[P1|M interleaved], P2b (proven) + scan block ----------------
// blocks [0,313): GEMM; block 313: exclusive prefix sum of cnt -> ptrs/pwork
// (hidden under the GEMM blocks; removes the separate k_scan launch).
__global__ __launch_bounds__(256) void k_gemm_pre(
    const float* __restrict__ X, const unsigned short* __restrict__ WpreT,
    const float* __restrict__ tabs,
    unsigned short* __restrict__ G, unsigned short* __restrict__ P2b,
    const int* __restrict__ cnt, int* __restrict__ ptrs, int* __restrict__ pwork)
{
  __shared__ __align__(16) unsigned short s_b[16*256]; // 8KB, swizzled elem ^= (n&7)<<3
  int tid = threadIdx.x;
  if (blockIdx.x == GEMM_BLOCKS){
    // two-pass scan: per-thread serial totals (cnt re-read from L2 on pass 2)
    int* s = (int*)s_b;
    constexpr int PER = (NN + 255)/256;  // 79
    int i0 = tid*PER;
    int tot = 0;
    for (int j = 0; j < PER; ++j){
      int i = i0 + j;
      if (i < NN) tot += cnt[i];
    }
    s[tid] = tot;
    __syncthreads();
    #pragma unroll
    for (int off = 1; off < 256; off <<= 1){
      int t = (tid >= off) ? s[tid - off] : 0;
      __syncthreads();
      s[tid] += t;
      __syncthreads();
    }
    int run = s[tid] - tot;   // exclusive base for this thread
    for (int j = 0; j < PER; ++j){
      int i = i0 + j;
      if (i < NN){
        ptrs[i]  = run;
        pwork[i] = run;
        run += cnt[i];
      }
    }
    if (tid == 255) ptrs[NN] = s[255];
    return;
  }
  int wv = tid >> 6, lane = tid & 63;
  int m0 = blockIdx.x*64 + wv*16;
  bool valid = (m0 < NN);
  int lo = lane & 15, hi = lane >> 4;
  bf16x8 a[8];
  if (valid){
    const float* xrow = X + (size_t)(m0 + lo)*256 + hi*8;
    #pragma unroll
    for (int kc = 0; kc < 8; ++kc){
      float4 f0 = *(const float4*)(xrow + kc*32);
      float4 f1 = *(const float4*)(xrow + kc*32 + 4);
      bf16x8 v;
      v[0]=(__bf16)f0.x; v[1]=(__bf16)f0.y; v[2]=(__bf16)f0.z; v[3]=(__bf16)f0.w;
      v[4]=(__bf16)f1.x; v[5]=(__bf16)f1.y; v[6]=(__bf16)f1.z; v[7]=(__bf16)f1.w;
      a[kc] = v;
    }
  }
  int sn = tid >> 4, sk0 = (tid & 15)*16;
  int sswz = (sn & 7) << 3;
  int rswz = (lo & 7) << 3;
  for (int nt = 0; nt < 48; ++nt){
    __syncthreads();
    {
      const unsigned short* gsrc = WpreT + (size_t)(nt*16 + sn)*256 + sk0;
      uint4 d0 = *(const uint4*)(gsrc);
      uint4 d1 = *(const uint4*)(gsrc + 8);
      *(uint4*)(s_b + sn*256 + (sk0 ^ sswz))       = d0;
      *(uint4*)(s_b + sn*256 + ((sk0 + 8) ^ sswz)) = d1;
    }
    __syncthreads();
    if (!valid) continue;
    f32x4 acc = {0.f, 0.f, 0.f, 0.f};
    #pragma unroll
    for (int kc = 0; kc < 8; ++kc){
      bf16x8 bfrag = *(const bf16x8*)(s_b + lo*256 + ((kc*32 + hi*8) ^ rswz));
      acc = __builtin_amdgcn_mfma_f32_16x16x32_bf16(a[kc], bfrag, acc, 0, 0, 0);
    }
    int n0 = nt*16;
    if (nt < 16){
      int j = n0 + lo;
      int elem = ((j >> 2) << 3) + 4 + (j & 3);
      unsigned short* grow = G + (size_t)(m0 + hi*4)*512 + elem;
      #pragma unroll
      for (int r = 0; r < 4; ++r) grow[(size_t)r*512] = f2bf(acc[r]);
    } else if (nt < 32){
      int j = n0 - 256 + lo;
      int elem = ((j >> 2) << 3) + (j & 3);
      unsigned short* grow = G + (size_t)(m0 + hi*4)*512 + elem;
      #pragma unroll
      for (int r = 0; r < 4; ++r) grow[(size_t)r*512] = f2bf(acc[r]);
    } else {
      int j = n0 - 512 + lo;
      float tcadd = tabs[TAB_TASKC + j];
      unsigned short* prow = P2b + (size_t)(m0 + hi*4)*256 + j;
      #pragma unroll
      for (int r = 0; r < 4; ++r) prow[(size_t)r*256] = f2bf(acc[r] + tcadd);
    }
  }
}

// ---------------- K2c: CSR build ----------------
__global__ __launch_bounds__(256) void k_csr_build(
    const int* __restrict__ eidx, const int* __restrict__ etype,
    int* __restrict__ pwork, unsigned int* __restrict__ srcet)
{
  int e = blockIdx.x*256 + threadIdx.x;
  if (e < NE){
    int dst = eidx[NE + e];
    int pos = atomicAdd(&pwork[dst], 1);
    srcet[pos] = (unsigned int)eidx[e] | ((unsigned int)etype[e] << 16);
  }
}

// ---------------- K3: fused attention + aggregate (proven round-6 structure, ECM table) ----------------
__global__ __launch_bounds__(256) void k_agg(
    const int* __restrict__ ptrs, const unsigned int* __restrict__ srcet,
    const unsigned short* __restrict__ G, const unsigned short* __restrict__ P2b,
    const float* __restrict__ tabs, const float* __restrict__ attW2,
    const float* __restrict__ attb2, const float* __restrict__ escale,
    unsigned short* __restrict__ updB)
{
  int node = blockIdx.x*4 + (threadIdx.x >> 6);
  if (node >= NN) return;
  int lane = threadIdx.x & 63, c0 = lane*4;
  ushort4 p2 = *(const ushort4*)(P2b + (size_t)node*256 + c0);
  float q0 = bf2f(p2.x), q1 = bf2f(p2.y), q2 = bf2f(p2.z), q3 = bf2f(p2.w);
  float4 w2 = *(const float4*)(attW2 + c0);
  float sc = escale[0], bb = attb2[0];
  float4 ms = *(const float4*)(tabs + TAB_MSG_SCALE + c0);
  float4 mb = *(const float4*)(tabs + TAB_MSG_BETA  + c0);
  float4 us = *(const float4*)(tabs + TAB_UPD_SCALE + c0);
  float4 ub = *(const float4*)(tabs + TAB_UPD_BETA  + c0);
  const float* ecm_base = tabs + TAB_ECM + (lane << 3);
  int start = ptrs[node], end = ptrs[node + 1];
  float ax = 0.f, ay = 0.f, az = 0.f, aw = 0.f, W = 0.f;
  unsigned int se0 = 0, se1 = 0;
  u16x8 g0 = {0,0,0,0,0,0,0,0};
  if (start < end){
    se0 = srcet[start];
    g0 = *(const u16x8*)(G + (size_t)(se0 & 0xFFFFu)*512 + lane*8);
    if (start + 1 < end) se1 = srcet[start + 1];
  }
  for (int i = start; i < end; ++i){
    u16x8 g1 = g0;
    unsigned int se2 = 0;
    if (i + 1 < end) g1 = *(const u16x8*)(G + (size_t)(se1 & 0xFFFFu)*512 + lane*8);
    if (i + 2 < end) se2 = srcet[i + 2];
    int et = (int)(se0 >> 16);
    const float* ecm = ecm_base + et*512;
    float4 ec = *(const float4*)(ecm);
    float4 em = *(const float4*)(ecm + 4);
    float part = gelu_fast(bf2f(g0[0]) + q0 + ec.x)*w2.x
               + gelu_fast(bf2f(g0[1]) + q1 + ec.y)*w2.y
               + gelu_fast(bf2f(g0[2]) + q2 + ec.z)*w2.z
               + gelu_fast(bf2f(g0[3]) + q3 + ec.w)*w2.w;
    #pragma unroll
    for (int off = 32; off; off >>= 1) part += __shfl_xor(part, off);
    float w = 1.0f + sc*tanh_fast(part + bb);
    ax += w*(bf2f(g0[4]) + em.x);
    ay += w*(bf2f(g0[5]) + em.y);
    az += w*(bf2f(g0[6]) + em.z);
    aw += w*(bf2f(g0[7]) + em.w);
    W += w;
    se0 = se1; se1 = se2; g0 = g1;
  }
  float d = fmaxf(W, 1.0f), rd = 1.0f / d;
  ushort4 st = { f2bf((ms.x*ax + mb.x*W)*rd*us.x + ub.x),
                 f2bf((ms.y*ay + mb.y*W)*rd*us.y + ub.y),
                 f2bf((ms.z*az + mb.z*W)*rd*us.z + ub.z),
                 f2bf((ms.w*aw + mb.w*W)*rd*us.w + ub.w) };
  *(ushort4*)(updB + (size_t)node*256 + c0) = st;
}

// ---------------- K4: 32-row dense MLP + residual + in-register LayerNorm (proven) ----------------
__device__ __forceinline__ bf16x8 ldA(const float* xrow, const unsigned short* urow, int ke){
  if (ke < 256){
    float4 f0 = *(const float4*)(xrow + ke);
    float4 f1 = *(const float4*)(xrow + ke + 4);
    bf16x8 v;
    v[0]=(__bf16)f0.x; v[1]=(__bf16)f0.y; v[2]=(__bf16)f0.z; v[3]=(__bf16)f0.w;
    v[4]=(__bf16)f1.x; v[5]=(__bf16)f1.y; v[6]=(__bf16)f1.z; v[7]=(__bf16)f1.w;
    return v;
  }
  return *(const bf16x8*)(urow + (ke - 256));
}

__global__ __launch_bounds__(256) void k_mlp(
    const float* __restrict__ X, const unsigned short* __restrict__ updB,
    const unsigned short* __restrict__ W1T, const unsigned short* __restrict__ W2T,
    const float* __restrict__ up_b1, const float* __restrict__ up_b2,
    const float* __restrict__ ln_g, const float* __restrict__ ln_b,
    float* __restrict__ out)
{
  __shared__ __align__(16) unsigned short s_H[32*256]; // bf16, ^=(row&7)<<3
  __shared__ float s_sum[4*32], s_sq[4*32];
  __shared__ float s_mu[32], s_rs[32];
  int m0 = blockIdx.x*32;
  int tid = threadIdx.x;
  int wv = tid >> 6, lane = tid & 63, lo = lane & 15, hi = lane >> 4;

  const float* x0 = X + (size_t)(m0 + lo)*256;
  const float* x1 = x0 + 16*256;
  const unsigned short* u0 = updB + (size_t)(m0 + lo)*256;
  const unsigned short* u1 = u0 + 16*256;

  f32x4 acc0[4], acc1[4];
  #pragma unroll
  for (int t = 0; t < 4; ++t){
    float b = up_b1[wv*64 + t*16 + lo];
    acc0[t] = (f32x4){b, b, b, b};
    acc1[t] = acc0[t];
  }
  #pragma unroll
  for (int kc = 0; kc < 16; ++kc){
    int ke = kc*32 + hi*8;
    bf16x8 a0 = ldA(x0, u0, ke);
    bf16x8 a1 = ldA(x1, u1, ke);
    #pragma unroll
    for (int t = 0; t < 4; ++t){
      int n = wv*64 + t*16 + lo;
      bf16x8 bf = *(const bf16x8*)(W1T + (size_t)n*512 + ke);
      acc0[t] = __builtin_amdgcn_mfma_f32_16x16x32_bf16(a0, bf, acc0[t], 0, 0, 0);
      acc1[t] = __builtin_amdgcn_mfma_f32_16x16x32_bf16(a1, bf, acc1[t], 0, 0, 0);
    }
  }
  #pragma unroll
  for (int t = 0; t < 4; ++t){
    #pragma unroll
    for (int r = 0; r < 4; ++r){
      int row0 = hi*4 + r, n = wv*64 + t*16 + lo;
      s_H[(row0 << 8) | (n ^ ((row0 & 7) << 3))] = f2bf(gelu_fast(acc0[t][r]));
      int row1 = row0 + 16;
      s_H[(row1 << 8) | (n ^ ((row1 & 7) << 3))] = f2bf(gelu_fast(acc1[t][r]));
    }
  }
  __syncthreads();

  f32x4 y0[4], y1[4];
  #pragma unroll
  for (int t = 0; t < 4; ++t){
    float b = up_b2[wv*64 + t*16 + lo];
    y0[t] = (f32x4){b, b, b, b};
    y1[t] = y0[t];
  }
  #pragma unroll
  for (int kc = 0; kc < 8; ++kc){
    int ke = kc*32 + hi*8;
    bf16x8 af0 = *(const bf16x8*)(s_H + ((lo << 8) | (ke ^ ((lo & 7) << 3))));
    int r1 = lo + 16;
    bf16x8 af1 = *(const bf16x8*)(s_H + ((r1 << 8) | (ke ^ ((r1 & 7) << 3))));
    #pragma unroll
    for (int t = 0; t < 4; ++t){
      int n = wv*64 + t*16 + lo;
      bf16x8 bf = *(const bf16x8*)(W2T + (size_t)n*256 + ke);
      y0[t] = __builtin_amdgcn_mfma_f32_16x16x32_bf16(af0, bf, y0[t], 0, 0, 0);
      y1[t] = __builtin_amdgcn_mfma_f32_16x16x32_bf16(af1, bf, y1[t], 0, 0, 0);
    }
  }

  #pragma unroll
  for (int t = 0; t < 4; ++t){
    #pragma unroll
    for (int r = 0; r < 4; ++r){
      int row0 = hi*4 + r, n = wv*64 + t*16 + lo;
      y0[t][r] += X[(size_t)(m0 + row0)*256 + n];
      y1[t][r] += X[(size_t)(m0 + row0 + 16)*256 + n];
    }
  }

  float ps[2][4], pq[2][4];
  #pragma unroll
  for (int r = 0; r < 4; ++r){
    float s0 = 0.f, q0 = 0.f, s1 = 0.f, q1 = 0.f;
    #pragma unroll
    for (int t = 0; t < 4; ++t){
      s0 += y0[t][r]; q0 += y0[t][r]*y0[t][r];
      s1 += y1[t][r]; q1 += y1[t][r]*y1[t][r];
    }
    #pragma unroll
    for (int off = 1; off < 16; off <<= 1){
      s0 += __shfl_xor(s0, off); q0 += __shfl_xor(q0, off);
      s1 += __shfl_xor(s1, off); q1 += __shfl_xor(q1, off);
    }
    ps[0][r] = s0; pq[0][r] = q0;
    ps[1][r] = s1; pq[1][r] = q1;
  }
  if (lo == 0){
    #pragma unroll
    for (int m = 0; m < 2; ++m){
      #pragma unroll
      for (int r = 0; r < 4; ++r){
        int row = m*16 + hi*4 + r;
        s_sum[wv*32 + row] = ps[m][r];
        s_sq [wv*32 + row] = pq[m][r];
      }
    }
  }
  __syncthreads();
  if (tid < 32){
    float sum = s_sum[tid] + s_sum[32 + tid] + s_sum[64 + tid] + s_sum[96 + tid];
    float sq  = s_sq[tid]  + s_sq[32 + tid]  + s_sq[64 + tid]  + s_sq[96 + tid];
    float mu = sum * (1.0f/256.0f);
    float var = sq * (1.0f/256.0f) - mu*mu;
    s_mu[tid] = mu;
    s_rs[tid] = rsqrtf(var + 1e-5f);
  }
  __syncthreads();

  #pragma unroll
  for (int t = 0; t < 4; ++t){
    int n = wv*64 + t*16 + lo;
    float lg = ln_g[n], lb = ln_b[n];
    #pragma unroll
    for (int r = 0; r < 4; ++r){
      int row0 = hi*4 + r, row1 = row0 + 16;
      out[(size_t)(m0 + row0)*256 + n] = (y0[t][r] - s_mu[row0]) * s_rs[row0] * lg + lb;
      out[(size_t)(m0 + row1)*256 + n] = (y1[t][r] - s_mu[row1]) * s_rs[row1] * lg + lb;
    }
  }
}

extern "C" void kernel_launch(void* const* d_in, const int* in_sizes, int n_in,
                              void* d_out, int out_size, void* d_ws, size_t ws_size,
                              hipStream_t stream)
{
  (void)in_sizes; (void)n_in; (void)out_size;
  if (ws_size < WS_NEED) return;
  const float* X      = (const float*)d_in[0];
  const int*   eidx   = (const int*)d_in[1];
  const int*   etype  = (const int*)d_in[2];
  const float* task   = (const float*)d_in[3];
  const float* eemb   = (const float*)d_in[4];
  const float* msg_W  = (const float*)d_in[5];
  const float* msg_b  = (const float*)d_in[6];
  const float* att_W1 = (const float*)d_in[7];
  const float* att_b1 = (const float*)d_in[8];
  const float* att_W2 = (const float*)d_in[9];
  const float* att_b2 = (const float*)d_in[10];
  const float* escale = (const float*)d_in[11];
  const float* ma_W1  = (const float*)d_in[12];
  const float* ma_b1  = (const float*)d_in[13];
  const float* ma_W2  = (const float*)d_in[14];
  const float* ma_b2  = (const float*)d_in[15];
  const float* up_W1  = (const float*)d_in[16];
  const float* up_b1  = (const float*)d_in[17];
  const float* up_W2  = (const float*)d_in[18];
  const float* up_b2  = (const float*)d_in[19];
  const float* ua_W1  = (const float*)d_in[20];
  const float* ua_b1  = (const float*)d_in[21];
  const float* ua_W2  = (const float*)d_in[22];
  const float* ua_b2  = (const float*)d_in[23];
  const float* ln_g   = (const float*)d_in[24];
  const float* ln_b   = (const float*)d_in[25];
  char* ws = (char*)d_ws;
  float* tabs = (float*)ws;
  unsigned short* WpreT = (unsigned short*)(ws + OFF_WPRET);
  unsigned short* W1T   = (unsigned short*)(ws + OFF_W1T);
  unsigned short* W2T   = (unsigned short*)(ws + OFF_W2T);
  int*          cnt   = (int*)(ws + OFF_CNT);
  int*          ptrs  = (int*)(ws + OFF_PTRS);
  int*          pwork = (int*)(ws + OFF_PWORK);
  unsigned int* srcet = (unsigned int*)(ws + OFF_SRCET);
  unsigned short* updB = (unsigned short*)(ws + OFF_UPDB);
  unsigned short* G    = (unsigned short*)(ws + OFF_G);
  unsigned short* P2b  = (unsigned short*)(ws + OFF_P2B);
  float* out = (float*)d_out;

  hipMemsetAsync(cnt, 0, (size_t)NN*4, stream);
  k_setup<<<2097, 256, 0, stream>>>(task, eemb, msg_W, msg_b, att_W1, att_b1,
                                    ma_W1, ma_b1, ma_W2, ma_b2,
                                    ua_W1, ua_b1, ua_W2, ua_b2,
                                    up_W1, up_W2, eidx,
                                    tabs, WpreT, W1T, W2T, cnt);
  k_gemm_pre<<<GEMM_BLOCKS + 1, 256, 0, stream>>>(X, WpreT, tabs, G, P2b,
                                                  cnt, ptrs, pwork);
  k_csr_build<<<(NE + 255)/256, 256, 0, stream>>>(eidx, etype, pwork, srcet);
  k_agg<<<(NN + 3)/4, 256, 0, stream>>>(ptrs, srcet, G, P2b, tabs,
                                        att_W2, att_b2, escale, updB);
  k_mlp<<<NN/32, 256, 0, stream>>>(X, updB, W1T, W2T, up_b1, up_b2,
                                   ln_g, ln_b, out);
}